// Round 6
// baseline (411.214 us; speedup 1.0000x reference)
//
#include <hip/hip_runtime.h>

typedef _Float16 half2v __attribute__((ext_vector_type(2)));
typedef _Float16 half4v __attribute__((ext_vector_type(4)));
typedef _Float16 f16x8 __attribute__((ext_vector_type(8)));
typedef float f32x4 __attribute__((ext_vector_type(4)));

#define NBKT_MAX 256     // n<=131072 with 512-node buckets
#define BKT_CAP  16384   // per-bucket pair capacity (mean 8163, sigma~90 -> +91 sigma)
#define OVF_CAP  8192    // overflow list capacity (expected use: 0)

// ---------------- weight precast: W1^T fp16 + W2 packed fp32 ----------------
// Wt[c][k] = fp16(W1[k][c])           (128x128 fp16, MFMA B-fragments)
// w2p[g*512 + c*8 + j] = W2[(g*8+j)][c]  (k-grouped, coalesced per-col 32B)
__global__ void wcast_kernel(const float* __restrict__ W1, _Float16* __restrict__ Wt,
                             const float* __restrict__ W2, float* __restrict__ w2p) {
    int t = blockIdx.x * 256 + threadIdx.x;
    if (t < 16384) {
        int k = t >> 7, c = t & 127;
        Wt[c * 128 + k] = (_Float16)W1[k * 128 + c];
    } else if (t < 16384 + 8192) {
        int i = t - 16384;
        int g = i >> 9, r = i & 511, c = r >> 3, j = r & 7;
        w2p[i] = W2[(g * 8 + j) * 64 + c];
    }
}

// ---------------- scan1 (+ fused dinv) ----------------
__global__ void scan1_kernel(const int* __restrict__ deg, int* __restrict__ rowstart,
                             int* __restrict__ blockSums, float* __restrict__ dinv, int n) {
    __shared__ int tmp[256];
    int t = threadIdx.x;
    int i = blockIdx.x * 256 + t;
    int v = (i < n) ? deg[i] : 0;
    if (i < n) dinv[i] = rsqrtf((float)(v + 1));  // +1 = self loop
    tmp[t] = v;
    __syncthreads();
#pragma unroll
    for (int off = 1; off < 256; off <<= 1) {
        int add = (t >= off) ? tmp[t - off] : 0;
        __syncthreads();
        tmp[t] += add;
        __syncthreads();
    }
    if (i < n) rowstart[i] = tmp[t] - v;
    if (t == 255) blockSums[blockIdx.x] = tmp[255];
}

__global__ void scan2_kernel(int* __restrict__ blockSums, int nb) {
    __shared__ int tmp[512];
    int t = threadIdx.x;
    int v = (t < nb) ? blockSums[t] : 0;
    tmp[t] = v;
    __syncthreads();
#pragma unroll
    for (int off = 1; off < 512; off <<= 1) {
        int add = (t >= off) ? tmp[t - off] : 0;
        __syncthreads();
        tmp[t] += add;
        __syncthreads();
    }
    if (t < nb) blockSums[t] = tmp[t] - v;
}

__global__ void scan3_kernel(int* __restrict__ rowstart, const int* __restrict__ blockSums, int n) {
    int i = blockIdx.x * blockDim.x + threadIdx.x;
    if (i < n) rowstart[i] += blockSums[i >> 8];
}

// ---------------- fused: degree + partition | GEMM1 (MFMA fp16, unscaled) ----------------
// Sort branch: per edge, global deg atomicAdd (replaces deg_kernel, hidden under
// the GEMM waves' MFMA pipe) + fixed-capacity bucket partition (no scan dependency).
// GEMM branch: h1 = fp16(x @ W1), NO dinv prescale (dinv not computed yet).
__global__ __launch_bounds__(256) void part_gemm1_kernel(
        const int* __restrict__ src, const int* __restrict__ dst,
        int* __restrict__ deg, int* __restrict__ bktCnt, int* __restrict__ ovfCnt,
        int2* __restrict__ ovfBuf, int2* __restrict__ pairPart, int E,
        const float* __restrict__ x, const _Float16* __restrict__ Wt,
        _Float16* __restrict__ h, int n, int nbkt) {
    __shared__ union {
        _Float16 xs_h[64][128];   // 16 KB
        struct { int cnt[NBKT_MAX]; int gbase[NBKT_MAX]; int off[NBKT_MAX]; } s;
    } u;
    int bid = blockIdx.x;
    int t = threadIdx.x;
    if (bid % 3 != 2) {
        // ---- GEMM1: 64 nodes x 128 cols, mfma_f32_16x16x32_f16 ----
        int gb = (bid / 3) * 2 + (bid % 3);
        int node0 = gb * 64;
        if (node0 >= n) return;

        // stage x tile -> fp16 LDS, swizzled: byte_in_row = seg*16 ^ ((row&7)<<4)
#pragma unroll
        for (int i = 0; i < 4; i++) {
            int fi = t + 256 * i;           // 1024 slots of 8 halves
            int row = fi >> 4, seg = fi & 15;
            float4 a = make_float4(0.f, 0.f, 0.f, 0.f);
            float4 b4 = make_float4(0.f, 0.f, 0.f, 0.f);
            if (node0 + row < n) {
                const float4* xr = (const float4*)(x + (size_t)(node0 + row) * 128 + seg * 8);
                a = xr[0]; b4 = xr[1];
            }
            f16x8 hv;
            hv[0] = (_Float16)a.x;  hv[1] = (_Float16)a.y;
            hv[2] = (_Float16)a.z;  hv[3] = (_Float16)a.w;
            hv[4] = (_Float16)b4.x; hv[5] = (_Float16)b4.y;
            hv[6] = (_Float16)b4.z; hv[7] = (_Float16)b4.w;
            int byte = row * 256 + ((seg * 16) ^ ((row & 7) << 4));
            *(f16x8*)((char*)&u.xs_h[0][0] + byte) = hv;
        }
        __syncthreads();

        int wid = t >> 6, l = t & 63;
        int row0 = wid * 16;                 // wave's 16-row slice
        int arow = row0 + (l & 15);
        int kgrp = l >> 4;                   // 0..3
        f32x4 acc[8];
#pragma unroll
        for (int ct = 0; ct < 8; ct++) acc[ct] = (f32x4){0.f, 0.f, 0.f, 0.f};

        const char* xbase = (const char*)&u.xs_h[0][0] + arow * 256;
#pragma unroll
        for (int ks = 0; ks < 4; ks++) {
            int abyte = ((ks * 64 + kgrp * 16) ^ ((arow & 7) << 4));
            f16x8 afrag = *(const f16x8*)(xbase + abyte);
#pragma unroll
            for (int ct = 0; ct < 8; ct++) {
                f16x8 bfrag = *(const f16x8*)(Wt + (ct * 16 + (l & 15)) * 128 + ks * 32 + kgrp * 8);
                acc[ct] = __builtin_amdgcn_mfma_f32_16x16x32_f16(afrag, bfrag, acc[ct], 0, 0, 0);
            }
        }

        // epilogue: C/D row = (l>>4)*4 + reg, col = ct*16 + (l&15); raw fp16
        int r0 = row0 + kgrp * 4;
#pragma unroll
        for (int ct = 0; ct < 8; ct++) {
            int col = ct * 16 + (l & 15);
#pragma unroll
            for (int r = 0; r < 4; r++) {
                int node = node0 + r0 + r;
                if (node < n)
                    h[(size_t)node * 128 + col] = (_Float16)acc[ct][r];
            }
        }
    } else {
        // ---- deg + partition: one 2048-edge tile per block ----
        int sb = bid / 3;
        int base = sb * 2048;
        if (base >= E) return;
        for (int i = t; i < nbkt; i += 256) u.s.cnt[i] = 0;
        __syncthreads();
        int s_[8], d_[8];
#pragma unroll
        for (int j = 0; j < 8; j++) {
            int e = base + t + 256 * j;
            s_[j] = -1;
            if (e < E) {
                s_[j] = src[e];
                d_[j] = dst[e];
                atomicAdd(&deg[d_[j]], 1);               // fused degree count
                atomicAdd(&u.s.cnt[d_[j] >> 9], 1);
            }
        }
        __syncthreads();
        for (int i = t; i < nbkt; i += 256) {
            u.s.off[i] = 0;
            int c = u.s.cnt[i];
            if (c > 0) u.s.gbase[i] = atomicAdd(&bktCnt[i], c);
        }
        __syncthreads();
#pragma unroll
        for (int j = 0; j < 8; j++) {
            if (s_[j] >= 0) {
                int b = d_[j] >> 9;
                int slot = u.s.gbase[b] + atomicAdd(&u.s.off[b], 1);
                if (slot < BKT_CAP) {
                    pairPart[(size_t)b * BKT_CAP + slot] = make_int2(s_[j], d_[j]);
                } else {
                    int op = atomicAdd(ovfCnt, 1);       // statistically never taken
                    if (op < OVF_CAP) ovfBuf[op] = make_int2(s_[j], d_[j]);
                }
            }
        }
    }
}

// ---------------- pass 2: exact-dst scatter within one bucket per block ----------------
__global__ __launch_bounds__(256) void scatter2_kernel(
        const int2* __restrict__ pairPart, const int* __restrict__ bktCnt,
        const int* __restrict__ ovfCnt, const int2* __restrict__ ovfBuf,
        const int* __restrict__ rowstart,
        int* __restrict__ srcSorted, int n) {
    __shared__ int lcur[512];
    int b = blockIdx.x;
    int t = threadIdx.x;
    int node0 = b << 9;
#pragma unroll
    for (int i = 0; i < 2; i++) {
        int node = node0 + t + 256 * i;
        if (node < n) lcur[t + 256 * i] = rowstart[node];
    }
    __syncthreads();
    int cnt = bktCnt[b];
    if (cnt > BKT_CAP) cnt = BKT_CAP;
    const int2* bp = pairPart + (size_t)b * BKT_CAP;
    for (int e = t; e < cnt; e += 256) {
        int2 p = bp[e];
        int pos = atomicAdd(&lcur[p.y - node0], 1);
        srcSorted[pos] = p.x;
    }
    int oc = *ovfCnt;
    if (oc > 0) {               // overflow drain (expected 0 iterations)
        if (oc > OVF_CAP) oc = OVF_CAP;
        for (int i = t; i < oc; i += 256) {
            int2 p = ovfBuf[i];
            if ((p.y >> 9) == b) {
                int pos = atomicAdd(&lcur[p.y - node0], 1);
                srcSorted[pos] = p.x;
            }
        }
    }
}

// ---------------- gather1_fused: h2 = relu(dg*agg(dinv.*h1) + b1); h3' = dinv*(h2@W2) ----------------
// Wave per node. dinv gathered cooperatively (1 VMEM per 64 edges) and shuffled
// with the src indices. h2 row goes to LDS (2KB), then the layer-2 GEMM runs
// in-block against packed W2 (L1/L2-resident) -> h2 never touches HBM.
__global__ __launch_bounds__(256) void gather1_fused(
        const int* __restrict__ srcS, const int* __restrict__ rowstart,
        const int* __restrict__ deg, const float* __restrict__ dinv,
        const _Float16* __restrict__ h1, const float* __restrict__ b1,
        const float* __restrict__ w2p, _Float16* __restrict__ h3, int n) {
    __shared__ float h2s[4][128];
    int t = threadIdx.x;
    int wv = t >> 6, lane = t & 63;
    int g = __builtin_amdgcn_readfirstlane(blockIdx.x * 4 + wv);
    float dg = 0.f;
    if (g < n) {
        dg = dinv[g];
        half2v sv0 = ((const half2v*)(h1 + (size_t)g * 128))[lane];
        float2 acc = make_float2(dg * (float)sv0.x, dg * (float)sv0.y);  // self term
        int beg = rowstart[g], end = beg + deg[g];
        int e = beg;
        while (e < end) {
            int rem = end - e;
            int sidx = (lane < rem) ? srcS[e + lane] : 0;
            float dvl = (lane < rem) ? dinv[sidx] : 0.f;
            int chunk = rem < 64 ? rem : 64;
            int j = 0;
            for (; j + 8 <= chunk; j += 8) {
                int s0 = __shfl(sidx, j + 0), s1 = __shfl(sidx, j + 1);
                int s2 = __shfl(sidx, j + 2), s3 = __shfl(sidx, j + 3);
                int s4 = __shfl(sidx, j + 4), s5 = __shfl(sidx, j + 5);
                int s6 = __shfl(sidx, j + 6), s7 = __shfl(sidx, j + 7);
                float w0 = __shfl(dvl, j + 0), w1 = __shfl(dvl, j + 1);
                float w2 = __shfl(dvl, j + 2), w3 = __shfl(dvl, j + 3);
                float w4 = __shfl(dvl, j + 4), w5 = __shfl(dvl, j + 5);
                float w6 = __shfl(dvl, j + 6), w7 = __shfl(dvl, j + 7);
                half2v u0 = ((const half2v*)(h1 + (size_t)s0 * 128))[lane];
                half2v u1 = ((const half2v*)(h1 + (size_t)s1 * 128))[lane];
                half2v u2 = ((const half2v*)(h1 + (size_t)s2 * 128))[lane];
                half2v u3 = ((const half2v*)(h1 + (size_t)s3 * 128))[lane];
                half2v u4 = ((const half2v*)(h1 + (size_t)s4 * 128))[lane];
                half2v u5 = ((const half2v*)(h1 + (size_t)s5 * 128))[lane];
                half2v u6 = ((const half2v*)(h1 + (size_t)s6 * 128))[lane];
                half2v u7 = ((const half2v*)(h1 + (size_t)s7 * 128))[lane];
                acc.x = fmaf(w0, (float)u0.x, acc.x); acc.y = fmaf(w0, (float)u0.y, acc.y);
                acc.x = fmaf(w1, (float)u1.x, acc.x); acc.y = fmaf(w1, (float)u1.y, acc.y);
                acc.x = fmaf(w2, (float)u2.x, acc.x); acc.y = fmaf(w2, (float)u2.y, acc.y);
                acc.x = fmaf(w3, (float)u3.x, acc.x); acc.y = fmaf(w3, (float)u3.y, acc.y);
                acc.x = fmaf(w4, (float)u4.x, acc.x); acc.y = fmaf(w4, (float)u4.y, acc.y);
                acc.x = fmaf(w5, (float)u5.x, acc.x); acc.y = fmaf(w5, (float)u5.y, acc.y);
                acc.x = fmaf(w6, (float)u6.x, acc.x); acc.y = fmaf(w6, (float)u6.y, acc.y);
                acc.x = fmaf(w7, (float)u7.x, acc.x); acc.y = fmaf(w7, (float)u7.y, acc.y);
            }
            for (; j < chunk; j++) {
                int s = __shfl(sidx, j);
                float w = __shfl(dvl, j);
                half2v u = ((const half2v*)(h1 + (size_t)s * 128))[lane];
                acc.x = fmaf(w, (float)u.x, acc.x);
                acc.y = fmaf(w, (float)u.y, acc.y);
            }
            e += chunk;
        }
        float2 b = ((const float2*)b1)[lane];
        acc.x = fmaxf(dg * acc.x + b.x, 0.f);
        acc.y = fmaxf(dg * acc.y + b.y, 0.f);
        h2s[wv][2 * lane]     = acc.x;       // h2 row -> LDS (never HBM)
        h2s[wv][2 * lane + 1] = acc.y;
    }
    __syncthreads();
    // in-block GEMM2: thread (wv, lane=col) dots h2s[wv][:] . W2[:,col]
    if (g < n) {
        float accd = 0.f;
#pragma unroll
        for (int kg = 0; kg < 16; kg++) {
            float4 wa = *(const float4*)(w2p + kg * 512 + lane * 8);
            float4 wb = *(const float4*)(w2p + kg * 512 + lane * 8 + 4);
            const float* hp = &h2s[wv][kg * 8];   // broadcast reads
            accd += hp[0] * wa.x + hp[1] * wa.y + hp[2] * wa.z + hp[3] * wa.w
                  + hp[4] * wb.x + hp[5] * wb.y + hp[6] * wb.z + hp[7] * wb.w;
        }
        h3[(size_t)g * 64 + lane] = (_Float16)(accd * dg);  // dinv prescale
    }
}

// ---------------- gather2: out = dg * agg(h3') + b2 ----------------
__global__ __launch_bounds__(256) void gather2_kernel(
        const int* __restrict__ srcS, const int* __restrict__ rowstart,
        const int* __restrict__ deg, const float* __restrict__ dinv,
        const _Float16* __restrict__ h3, const float* __restrict__ b2,
        float* __restrict__ out, int n) {
    int t = threadIdx.x;
    int g = __builtin_amdgcn_readfirstlane(blockIdx.x * 4 + (t >> 6));
    int lane = t & 63;
    if (g >= n) return;
    float dg = dinv[g];
    float acc = (float)h3[(size_t)g * 64 + lane];   // self term (pre-scaled)
    int beg = rowstart[g], end = beg + deg[g];
    int e = beg;
    while (e < end) {
        int rem = end - e;
        int sv = (lane < rem) ? srcS[e + lane] : 0;
        int chunk = rem < 64 ? rem : 64;
        int j = 0;
        for (; j + 8 <= chunk; j += 8) {
            int s0 = __shfl(sv, j + 0), s1 = __shfl(sv, j + 1);
            int s2 = __shfl(sv, j + 2), s3 = __shfl(sv, j + 3);
            int s4 = __shfl(sv, j + 4), s5 = __shfl(sv, j + 5);
            int s6 = __shfl(sv, j + 6), s7 = __shfl(sv, j + 7);
            float u0 = (float)h3[(size_t)s0 * 64 + lane];
            float u1 = (float)h3[(size_t)s1 * 64 + lane];
            float u2 = (float)h3[(size_t)s2 * 64 + lane];
            float u3 = (float)h3[(size_t)s3 * 64 + lane];
            float u4 = (float)h3[(size_t)s4 * 64 + lane];
            float u5 = (float)h3[(size_t)s5 * 64 + lane];
            float u6 = (float)h3[(size_t)s6 * 64 + lane];
            float u7 = (float)h3[(size_t)s7 * 64 + lane];
            acc += u0 + u1 + u2 + u3 + u4 + u5 + u6 + u7;
        }
        for (; j < chunk; j++) {
            int s = __shfl(sv, j);
            acc += (float)h3[(size_t)s * 64 + lane];
        }
        e += chunk;
    }
    out[(size_t)g * 64 + lane] = dg * acc + b2[lane];
}

extern "C" void kernel_launch(void* const* d_in, const int* in_sizes, int n_in,
                              void* d_out, int out_size, void* d_ws, size_t ws_size,
                              hipStream_t stream) {
    const float* x  = (const float*)d_in[0];
    const int*   ei = (const int*)d_in[1];
    const float* W1 = (const float*)d_in[2];
    const float* b1 = (const float*)d_in[3];
    const float* W2 = (const float*)d_in[4];
    const float* b2 = (const float*)d_in[5];
    float* out = (float*)d_out;

    const int n = in_sizes[0] / 128;   // 100000
    const int E = in_sizes[1] / 2;     // 1600000
    const int* src = ei;
    const int* dst = ei + E;
    const int nb = (n + 255) / 256;
    const int nbkt = (n + 511) >> 9;   // 196 coarse buckets (512 nodes each)

    char* ws = (char*)d_ws;
    size_t off = 0;
    auto carve = [&](size_t bytes) -> char* {
        char* p = ws + off;
        off += (bytes + 255) & ~(size_t)255;
        return p;
    };
    // deg/bktCnt/ovfCnt contiguous -> single memset
    int*   deg       = (int*)carve((size_t)n * 4);
    int*   bktCnt    = (int*)carve((size_t)NBKT_MAX * 4);
    int*   ovfCnt    = (int*)carve(4);
    size_t msz       = (size_t)((char*)ovfCnt - (char*)deg) + 256;
    float* dinv      = (float*)carve((size_t)n * 4);
    int*   rowstart  = (int*)carve((size_t)n * 4);
    int*   blockSums = (int*)carve((size_t)nb * 4);
    int*   srcSorted = (int*)carve((size_t)E * 4);
    _Float16* Wt     = (_Float16*)carve((size_t)128 * 128 * 2);    // W1^T fp16
    float* w2p       = (float*)carve((size_t)128 * 64 * 4);        // W2 packed fp32
    int2*  ovfBuf    = (int2*)carve((size_t)OVF_CAP * 8);
    int2*  pairPart  = (int2*)carve((size_t)nbkt * BKT_CAP * 8);   // 25.7 MB
    _Float16* h1     = (_Float16*)carve((size_t)n * 128 * 2);      // raw x@W1 fp16
    _Float16* h3     = (_Float16*)carve((size_t)n * 64 * 2);       // dinv*(h2@W2) fp16

    hipMemsetAsync(deg, 0, msz, stream);

    wcast_kernel<<<96, 256, 0, stream>>>(W1, Wt, W2, w2p);

    // fused degree+partition | gemm1 (2 GEMM : 1 sort per triple); no scan dep
    int sortBlocks = (E + 2047) / 2048;             // 782
    int gemmBlocks = (n + 63) / 64;                 // 1563
    int triples = sortBlocks;
    int gtr = (gemmBlocks + 1) / 2;
    if (gtr > triples) triples = gtr;
    int G = triples * 3;
    part_gemm1_kernel<<<G, 256, 0, stream>>>(src, dst, deg, bktCnt, ovfCnt, ovfBuf,
                                             pairPart, E, x, Wt, h1, n, nbkt);

    scan1_kernel<<<nb, 256, 0, stream>>>(deg, rowstart, blockSums, dinv, n);
    scan2_kernel<<<1, 512, 0, stream>>>(blockSums, nb);
    scan3_kernel<<<(n + 255) / 256, 256, 0, stream>>>(rowstart, blockSums, n);

    // exact scatter within buckets
    scatter2_kernel<<<nbkt, 256, 0, stream>>>(pairPart, bktCnt, ovfCnt, ovfBuf,
                                              rowstart, srcSorted, n);

    // layer 1 aggregation + fused layer-2 GEMM (h2 stays in LDS)
    gather1_fused<<<(n + 3) / 4, 256, 0, stream>>>(srcSorted, rowstart, deg, dinv,
                                                   h1, b1, w2p, h3, n);

    // layer 2 aggregation
    gather2_kernel<<<(n + 3) / 4, 256, 0, stream>>>(srcSorted, rowstart, deg, dinv,
                                                    h3, b2, out, n);
}

// Round 7
// 386.696 us; speedup vs baseline: 1.0634x; 1.0634x over previous
//
#include <hip/hip_runtime.h>

typedef _Float16 half2v __attribute__((ext_vector_type(2)));
typedef _Float16 half4v __attribute__((ext_vector_type(4)));
typedef _Float16 f16x8 __attribute__((ext_vector_type(8)));
typedef float f32x4 __attribute__((ext_vector_type(4)));

#define NBKT_MAX 256     // n<=131072 with 512-node buckets
#define BKT_CAP  16384   // per-bucket pair capacity (mean 8163, sigma~90 -> +91 sigma)
#define OVF_CAP  8192    // overflow list capacity (expected use: 0)

// ---------------- W1 cast + transpose: Wt[col][k] fp16 ----------------
__global__ void wcast_kernel(const float* __restrict__ W, _Float16* __restrict__ Wt) {
    int t = blockIdx.x * 256 + threadIdx.x;
    if (t < 128 * 128) {
        int k = t >> 7, c = t & 127;
        Wt[c * 128 + k] = (_Float16)W[k * 128 + c];
    }
}

// ---------------- scan1 (+ fused dinv) ----------------
__global__ void scan1_kernel(const int* __restrict__ deg, int* __restrict__ rowstart,
                             int* __restrict__ blockSums, float* __restrict__ dinv, int n) {
    __shared__ int tmp[256];
    int t = threadIdx.x;
    int i = blockIdx.x * 256 + t;
    int v = (i < n) ? deg[i] : 0;
    if (i < n) dinv[i] = rsqrtf((float)(v + 1));  // +1 = self loop
    tmp[t] = v;
    __syncthreads();
#pragma unroll
    for (int off = 1; off < 256; off <<= 1) {
        int add = (t >= off) ? tmp[t - off] : 0;
        __syncthreads();
        tmp[t] += add;
        __syncthreads();
    }
    if (i < n) rowstart[i] = tmp[t] - v;
    if (t == 255) blockSums[blockIdx.x] = tmp[255];
}

__global__ void scan2_kernel(int* __restrict__ blockSums, int nb) {
    __shared__ int tmp[512];
    int t = threadIdx.x;
    int v = (t < nb) ? blockSums[t] : 0;
    tmp[t] = v;
    __syncthreads();
#pragma unroll
    for (int off = 1; off < 512; off <<= 1) {
        int add = (t >= off) ? tmp[t - off] : 0;
        __syncthreads();
        tmp[t] += add;
        __syncthreads();
    }
    if (t < nb) blockSums[t] = tmp[t] - v;
}

__global__ void scan3_kernel(int* __restrict__ rowstart, const int* __restrict__ blockSums, int n) {
    int i = blockIdx.x * blockDim.x + threadIdx.x;
    if (i < n) rowstart[i] += blockSums[i >> 8];
}

// ---------------- scale_h1: h1[i][:] *= dinv[i]  (streaming, ~51MB r+w) ----------------
__global__ __launch_bounds__(256) void scale_h1_kernel(_Float16* __restrict__ h1,
                                                       const float* __restrict__ dinv, int n) {
    int j = blockIdx.x * 256 + threadIdx.x;   // one f16x8 (16B) per thread
    if (j < n * 16) {
        float dv = dinv[j >> 4];
        f16x8 v = ((const f16x8*)h1)[j];
#pragma unroll
        for (int k = 0; k < 8; k++) v[k] = (_Float16)((float)v[k] * dv);
        ((f16x8*)h1)[j] = v;
    }
}

// ---------------- fused: degree + partition | GEMM1 (MFMA fp16, unscaled) ----------------
// Sort branch: per edge, global deg atomicAdd (hidden under the GEMM waves' MFMA
// pipe) + fixed-capacity bucket partition (no scan dependency). GEMM branch:
// h1 = fp16(x @ W1), unscaled (dinv scaled in by scale_h1 afterwards).
__global__ __launch_bounds__(256) void part_gemm1_kernel(
        const int* __restrict__ src, const int* __restrict__ dst,
        int* __restrict__ deg, int* __restrict__ bktCnt, int* __restrict__ ovfCnt,
        int2* __restrict__ ovfBuf, int2* __restrict__ pairPart, int E,
        const float* __restrict__ x, const _Float16* __restrict__ Wt,
        _Float16* __restrict__ h, int n, int nbkt) {
    __shared__ union {
        _Float16 xs_h[64][128];   // 16 KB
        struct { int cnt[NBKT_MAX]; int gbase[NBKT_MAX]; int off[NBKT_MAX]; } s;
    } u;
    int bid = blockIdx.x;
    int t = threadIdx.x;
    if (bid % 3 != 2) {
        // ---- GEMM1: 64 nodes x 128 cols, mfma_f32_16x16x32_f16 ----
        int gb = (bid / 3) * 2 + (bid % 3);
        int node0 = gb * 64;
        if (node0 >= n) return;

        // stage x tile -> fp16 LDS, swizzled: byte_in_row = seg*16 ^ ((row&7)<<4)
#pragma unroll
        for (int i = 0; i < 4; i++) {
            int fi = t + 256 * i;           // 1024 slots of 8 halves
            int row = fi >> 4, seg = fi & 15;
            float4 a = make_float4(0.f, 0.f, 0.f, 0.f);
            float4 b4 = make_float4(0.f, 0.f, 0.f, 0.f);
            if (node0 + row < n) {
                const float4* xr = (const float4*)(x + (size_t)(node0 + row) * 128 + seg * 8);
                a = xr[0]; b4 = xr[1];
            }
            f16x8 hv;
            hv[0] = (_Float16)a.x;  hv[1] = (_Float16)a.y;
            hv[2] = (_Float16)a.z;  hv[3] = (_Float16)a.w;
            hv[4] = (_Float16)b4.x; hv[5] = (_Float16)b4.y;
            hv[6] = (_Float16)b4.z; hv[7] = (_Float16)b4.w;
            int byte = row * 256 + ((seg * 16) ^ ((row & 7) << 4));
            *(f16x8*)((char*)&u.xs_h[0][0] + byte) = hv;
        }
        __syncthreads();

        int wid = t >> 6, l = t & 63;
        int row0 = wid * 16;                 // wave's 16-row slice
        int arow = row0 + (l & 15);
        int kgrp = l >> 4;                   // 0..3
        f32x4 acc[8];
#pragma unroll
        for (int ct = 0; ct < 8; ct++) acc[ct] = (f32x4){0.f, 0.f, 0.f, 0.f};

        const char* xbase = (const char*)&u.xs_h[0][0] + arow * 256;
#pragma unroll
        for (int ks = 0; ks < 4; ks++) {
            int abyte = ((ks * 64 + kgrp * 16) ^ ((arow & 7) << 4));
            f16x8 afrag = *(const f16x8*)(xbase + abyte);
#pragma unroll
            for (int ct = 0; ct < 8; ct++) {
                f16x8 bfrag = *(const f16x8*)(Wt + (ct * 16 + (l & 15)) * 128 + ks * 32 + kgrp * 8);
                acc[ct] = __builtin_amdgcn_mfma_f32_16x16x32_f16(afrag, bfrag, acc[ct], 0, 0, 0);
            }
        }

        // epilogue: C/D row = (l>>4)*4 + reg, col = ct*16 + (l&15); raw fp16
        int r0 = row0 + kgrp * 4;
#pragma unroll
        for (int ct = 0; ct < 8; ct++) {
            int col = ct * 16 + (l & 15);
#pragma unroll
            for (int r = 0; r < 4; r++) {
                int node = node0 + r0 + r;
                if (node < n)
                    h[(size_t)node * 128 + col] = (_Float16)acc[ct][r];
            }
        }
    } else {
        // ---- deg + partition: one 2048-edge tile per block ----
        int sb = bid / 3;
        int base = sb * 2048;
        if (base >= E) return;
        for (int i = t; i < nbkt; i += 256) u.s.cnt[i] = 0;
        __syncthreads();
        int s_[8], d_[8];
#pragma unroll
        for (int j = 0; j < 8; j++) {
            int e = base + t + 256 * j;
            s_[j] = -1;
            if (e < E) {
                s_[j] = src[e];
                d_[j] = dst[e];
                atomicAdd(&deg[d_[j]], 1);               // fused degree count
                atomicAdd(&u.s.cnt[d_[j] >> 9], 1);
            }
        }
        __syncthreads();
        for (int i = t; i < nbkt; i += 256) {
            u.s.off[i] = 0;
            int c = u.s.cnt[i];
            if (c > 0) u.s.gbase[i] = atomicAdd(&bktCnt[i], c);
        }
        __syncthreads();
#pragma unroll
        for (int j = 0; j < 8; j++) {
            if (s_[j] >= 0) {
                int b = d_[j] >> 9;
                int slot = u.s.gbase[b] + atomicAdd(&u.s.off[b], 1);
                if (slot < BKT_CAP) {
                    pairPart[(size_t)b * BKT_CAP + slot] = make_int2(s_[j], d_[j]);
                } else {
                    int op = atomicAdd(ovfCnt, 1);       // statistically never taken
                    if (op < OVF_CAP) ovfBuf[op] = make_int2(s_[j], d_[j]);
                }
            }
        }
    }
}

// ---------------- pass 2: exact-dst scatter within one bucket per block ----------------
__global__ __launch_bounds__(256) void scatter2_kernel(
        const int2* __restrict__ pairPart, const int* __restrict__ bktCnt,
        const int* __restrict__ ovfCnt, const int2* __restrict__ ovfBuf,
        const int* __restrict__ rowstart,
        int* __restrict__ srcSorted, int n) {
    __shared__ int lcur[512];
    int b = blockIdx.x;
    int t = threadIdx.x;
    int node0 = b << 9;
#pragma unroll
    for (int i = 0; i < 2; i++) {
        int node = node0 + t + 256 * i;
        if (node < n) lcur[t + 256 * i] = rowstart[node];
    }
    __syncthreads();
    int cnt = bktCnt[b];
    if (cnt > BKT_CAP) cnt = BKT_CAP;
    const int2* bp = pairPart + (size_t)b * BKT_CAP;
    for (int e = t; e < cnt; e += 256) {
        int2 p = bp[e];
        int pos = atomicAdd(&lcur[p.y - node0], 1);
        srcSorted[pos] = p.x;
    }
    int oc = *ovfCnt;
    if (oc > 0) {               // overflow drain (expected 0 iterations)
        if (oc > OVF_CAP) oc = OVF_CAP;
        for (int i = t; i < oc; i += 256) {
            int2 p = ovfBuf[i];
            if ((p.y >> 9) == b) {
                int pos = atomicAdd(&lcur[p.y - node0], 1);
                srcSorted[pos] = p.x;
            }
        }
    }
}

// ---------------- gather1: h2 = relu(dg * agg(h1') + b1)  [proven R4 shape] ----------------
__global__ __launch_bounds__(256) void gather1_kernel(
        const int* __restrict__ srcS, const int* __restrict__ rowstart,
        const int* __restrict__ deg, const float* __restrict__ dinv,
        const _Float16* __restrict__ h1, const float* __restrict__ b1,
        float* __restrict__ h2, int n) {
    int t = threadIdx.x;
    int g = __builtin_amdgcn_readfirstlane(blockIdx.x * 4 + (t >> 6));
    int lane = t & 63;
    if (g >= n) return;

    float dg = dinv[g];
    half2v sv0 = ((const half2v*)(h1 + (size_t)g * 128))[lane];  // self term (pre-scaled)
    float2 acc = make_float2((float)sv0.x, (float)sv0.y);
    int beg = rowstart[g], end = beg + deg[g];
    int e = beg;
    while (e < end) {
        int rem = end - e;
        int sv = (lane < rem) ? srcS[e + lane] : 0;   // 1 coalesced load / 64 edges
        int chunk = rem < 64 ? rem : 64;
        int j = 0;
        for (; j + 8 <= chunk; j += 8) {
            int s0 = __shfl(sv, j + 0), s1 = __shfl(sv, j + 1);
            int s2 = __shfl(sv, j + 2), s3 = __shfl(sv, j + 3);
            int s4 = __shfl(sv, j + 4), s5 = __shfl(sv, j + 5);
            int s6 = __shfl(sv, j + 6), s7 = __shfl(sv, j + 7);
            half2v u0 = ((const half2v*)(h1 + (size_t)s0 * 128))[lane];
            half2v u1 = ((const half2v*)(h1 + (size_t)s1 * 128))[lane];
            half2v u2 = ((const half2v*)(h1 + (size_t)s2 * 128))[lane];
            half2v u3 = ((const half2v*)(h1 + (size_t)s3 * 128))[lane];
            half2v u4 = ((const half2v*)(h1 + (size_t)s4 * 128))[lane];
            half2v u5 = ((const half2v*)(h1 + (size_t)s5 * 128))[lane];
            half2v u6 = ((const half2v*)(h1 + (size_t)s6 * 128))[lane];
            half2v u7 = ((const half2v*)(h1 + (size_t)s7 * 128))[lane];
            acc.x += (float)u0.x; acc.y += (float)u0.y;
            acc.x += (float)u1.x; acc.y += (float)u1.y;
            acc.x += (float)u2.x; acc.y += (float)u2.y;
            acc.x += (float)u3.x; acc.y += (float)u3.y;
            acc.x += (float)u4.x; acc.y += (float)u4.y;
            acc.x += (float)u5.x; acc.y += (float)u5.y;
            acc.x += (float)u6.x; acc.y += (float)u6.y;
            acc.x += (float)u7.x; acc.y += (float)u7.y;
        }
        for (; j < chunk; j++) {
            int s = __shfl(sv, j);
            half2v u = ((const half2v*)(h1 + (size_t)s * 128))[lane];
            acc.x += (float)u.x; acc.y += (float)u.y;
        }
        e += chunk;
    }
    float2 b = ((const float2*)b1)[lane];
    acc.x = fmaxf(dg * acc.x + b.x, 0.f);
    acc.y = fmaxf(dg * acc.y + b.y, 0.f);
    ((float2*)(h2 + (size_t)g * 128))[lane] = acc;
}

// ---------------- GEMM2: h3'[N,64] = fp16( dinv * (h2[N,128] @ W2[128,64]) ) ----------------
__global__ __launch_bounds__(256) void gemm_nk64(const float* __restrict__ x,
                                                 const float* __restrict__ W,
                                                 const float* __restrict__ dinv,
                                                 _Float16* __restrict__ h, int n) {
    __shared__ float xs[32][128];
    int t = threadIdx.x;
    int node0 = blockIdx.x * 32;
#pragma unroll
    for (int i = 0; i < 4; i++) {
        int fi = t + 256 * i;
        int row = fi >> 5, cv = fi & 31;
        float4 v = make_float4(0.f, 0.f, 0.f, 0.f);
        if (node0 + row < n) v = ((const float4*)x)[(size_t)(node0 + row) * 32 + cv];
        ((float4*)(&xs[0][0]))[fi] = v;
    }
    __syncthreads();

    int tx = t & 15, ty = t >> 4;
    int c0 = tx * 4;
    float acc[2][4];
#pragma unroll
    for (int i = 0; i < 2; i++)
#pragma unroll
        for (int j = 0; j < 4; j++) acc[i][j] = 0.f;

    for (int k = 0; k < 128; k++) {
        float4 w = *(const float4*)(W + k * 64 + c0);
#pragma unroll
        for (int i = 0; i < 2; i++) {
            float xval = xs[ty + 16 * i][k];
            acc[i][0] += xval * w.x;
            acc[i][1] += xval * w.y;
            acc[i][2] += xval * w.z;
            acc[i][3] += xval * w.w;
        }
    }
#pragma unroll
    for (int i = 0; i < 2; i++) {
        int node = node0 + ty + 16 * i;
        if (node < n) {
            float dv = dinv[node];
            half4v hv;
            hv.x = (_Float16)(acc[i][0] * dv);
            hv.y = (_Float16)(acc[i][1] * dv);
            hv.z = (_Float16)(acc[i][2] * dv);
            hv.w = (_Float16)(acc[i][3] * dv);
            *(half4v*)(h + (size_t)node * 64 + c0) = hv;
        }
    }
}

// ---------------- gather2: out = dg * agg(h3') + b2 ----------------
__global__ __launch_bounds__(256) void gather2_kernel(
        const int* __restrict__ srcS, const int* __restrict__ rowstart,
        const int* __restrict__ deg, const float* __restrict__ dinv,
        const _Float16* __restrict__ h3, const float* __restrict__ b2,
        float* __restrict__ out, int n) {
    int t = threadIdx.x;
    int g = __builtin_amdgcn_readfirstlane(blockIdx.x * 4 + (t >> 6));
    int lane = t & 63;
    if (g >= n) return;
    float dg = dinv[g];
    float acc = (float)h3[(size_t)g * 64 + lane];   // self term (pre-scaled)
    int beg = rowstart[g], end = beg + deg[g];
    int e = beg;
    while (e < end) {
        int rem = end - e;
        int sv = (lane < rem) ? srcS[e + lane] : 0;
        int chunk = rem < 64 ? rem : 64;
        int j = 0;
        for (; j + 8 <= chunk; j += 8) {
            int s0 = __shfl(sv, j + 0), s1 = __shfl(sv, j + 1);
            int s2 = __shfl(sv, j + 2), s3 = __shfl(sv, j + 3);
            int s4 = __shfl(sv, j + 4), s5 = __shfl(sv, j + 5);
            int s6 = __shfl(sv, j + 6), s7 = __shfl(sv, j + 7);
            float u0 = (float)h3[(size_t)s0 * 64 + lane];
            float u1 = (float)h3[(size_t)s1 * 64 + lane];
            float u2 = (float)h3[(size_t)s2 * 64 + lane];
            float u3 = (float)h3[(size_t)s3 * 64 + lane];
            float u4 = (float)h3[(size_t)s4 * 64 + lane];
            float u5 = (float)h3[(size_t)s5 * 64 + lane];
            float u6 = (float)h3[(size_t)s6 * 64 + lane];
            float u7 = (float)h3[(size_t)s7 * 64 + lane];
            acc += u0 + u1 + u2 + u3 + u4 + u5 + u6 + u7;
        }
        for (; j < chunk; j++) {
            int s = __shfl(sv, j);
            acc += (float)h3[(size_t)s * 64 + lane];
        }
        e += chunk;
    }
    out[(size_t)g * 64 + lane] = dg * acc + b2[lane];
}

extern "C" void kernel_launch(void* const* d_in, const int* in_sizes, int n_in,
                              void* d_out, int out_size, void* d_ws, size_t ws_size,
                              hipStream_t stream) {
    const float* x  = (const float*)d_in[0];
    const int*   ei = (const int*)d_in[1];
    const float* W1 = (const float*)d_in[2];
    const float* b1 = (const float*)d_in[3];
    const float* W2 = (const float*)d_in[4];
    const float* b2 = (const float*)d_in[5];
    float* out = (float*)d_out;

    const int n = in_sizes[0] / 128;   // 100000
    const int E = in_sizes[1] / 2;     // 1600000
    const int* src = ei;
    const int* dst = ei + E;
    const int nb = (n + 255) / 256;
    const int nbkt = (n + 511) >> 9;   // 196 coarse buckets (512 nodes each)

    char* ws = (char*)d_ws;
    size_t off = 0;
    auto carve = [&](size_t bytes) -> char* {
        char* p = ws + off;
        off += (bytes + 255) & ~(size_t)255;
        return p;
    };
    // deg/bktCnt/ovfCnt contiguous -> single memset
    int*   deg       = (int*)carve((size_t)n * 4);
    int*   bktCnt    = (int*)carve((size_t)NBKT_MAX * 4);
    int*   ovfCnt    = (int*)carve(4);
    size_t msz       = (size_t)((char*)ovfCnt - (char*)deg) + 256;
    float* dinv      = (float*)carve((size_t)n * 4);
    int*   rowstart  = (int*)carve((size_t)n * 4);
    int*   blockSums = (int*)carve((size_t)nb * 4);
    int*   srcSorted = (int*)carve((size_t)E * 4);
    _Float16* Wt     = (_Float16*)carve((size_t)128 * 128 * 2);    // W1^T fp16
    int2*  ovfBuf    = (int2*)carve((size_t)OVF_CAP * 8);
    _Float16* h1     = (_Float16*)carve((size_t)n * 128 * 2);      // x@W1 fp16 (scaled in-place); then h3
    float* bufB      = (float*)carve((size_t)n * 128 * 4);         // pairPart (pass1-2), then h2
    int2*  pairPart  = (int2*)bufB;    // 25.7MB <= 51.2MB, dead before gather1 writes h2
    _Float16* h3     = h1;             // gemm_nk64 writes after gather1 finishes reading h1

    hipMemsetAsync(deg, 0, msz, stream);

    wcast_kernel<<<64, 256, 0, stream>>>(W1, Wt);

    // fused degree+partition | gemm1 (2 GEMM : 1 sort per triple); no scan dep
    int sortBlocks = (E + 2047) / 2048;             // 782
    int gemmBlocks = (n + 63) / 64;                 // 1563
    int triples = sortBlocks;
    int gtr = (gemmBlocks + 1) / 2;
    if (gtr > triples) triples = gtr;
    int G = triples * 3;
    part_gemm1_kernel<<<G, 256, 0, stream>>>(src, dst, deg, bktCnt, ovfCnt, ovfBuf,
                                             pairPart, E, x, Wt, h1, n, nbkt);

    scan1_kernel<<<nb, 256, 0, stream>>>(deg, rowstart, blockSums, dinv, n);
    scan2_kernel<<<1, 512, 0, stream>>>(blockSums, nb);
    scan3_kernel<<<(n + 255) / 256, 256, 0, stream>>>(rowstart, blockSums, n);

    // h1 *= dinv (restores the prescaled-h1 invariant for the proven gather1)
    scale_h1_kernel<<<(n * 16 + 255) / 256, 256, 0, stream>>>(h1, dinv, n);

    // exact scatter within buckets
    scatter2_kernel<<<nbkt, 256, 0, stream>>>(pairPart, bktCnt, ovfCnt, ovfBuf,
                                              rowstart, srcSorted, n);

    // layer 1 aggregation: h2 = relu(dg * agg(h1') + b1)
    gather1_kernel<<<(n + 3) / 4, 256, 0, stream>>>(srcSorted, rowstart, deg, dinv,
                                                    h1, b1, bufB, n);

    // layer 2: h3' = fp16(dinv * (h2@W2)) (reuses h1 buffer) ; out = dg * agg(h3') + b2
    gemm_nk64<<<(n + 31) / 32, 256, 0, stream>>>(bufB, W2, dinv, h3, n);
    gather2_kernel<<<(n + 3) / 4, 256, 0, stream>>>(srcSorted, rowstart, deg, dinv,
                                                    h3, b2, out, n);
}

// Round 8
// 368.564 us; speedup vs baseline: 1.1157x; 1.0492x over previous
//
#include <hip/hip_runtime.h>

typedef _Float16 half2v __attribute__((ext_vector_type(2)));
typedef _Float16 half4v __attribute__((ext_vector_type(4)));
typedef _Float16 f16x8 __attribute__((ext_vector_type(8)));
typedef float f32x4 __attribute__((ext_vector_type(4)));

#define NBKT_MAX 256     // n<=131072 with 512-node buckets
#define BKT_CAP  16384   // per-bucket pair capacity (mean 8163, sigma~90 -> +91 sigma)
#define OVF_CAP  8192    // overflow list capacity (expected use: 0)
#define SRC_MASK 0x1FFFF // 17-bit src (n < 131072)

// ---------------- W1 cast + transpose: Wt[col][k] fp16 ----------------
__global__ void wcast_kernel(const float* __restrict__ W, _Float16* __restrict__ Wt) {
    int t = blockIdx.x * 256 + threadIdx.x;
    if (t < 128 * 128) {
        int k = t >> 7, c = t & 127;
        Wt[c * 128 + k] = (_Float16)W[k * 128 + c];
    }
}

// ---------------- scan1 (+ fused dinv) ----------------
__global__ void scan1_kernel(const int* __restrict__ deg, int* __restrict__ rowstart,
                             int* __restrict__ blockSums, float* __restrict__ dinv, int n) {
    __shared__ int tmp[256];
    int t = threadIdx.x;
    int i = blockIdx.x * 256 + t;
    int v = (i < n) ? deg[i] : 0;
    if (i < n) dinv[i] = rsqrtf((float)(v + 1));  // +1 = self loop
    tmp[t] = v;
    __syncthreads();
#pragma unroll
    for (int off = 1; off < 256; off <<= 1) {
        int add = (t >= off) ? tmp[t - off] : 0;
        __syncthreads();
        tmp[t] += add;
        __syncthreads();
    }
    if (i < n) rowstart[i] = tmp[t] - v;
    if (t == 255) blockSums[blockIdx.x] = tmp[255];
}

__global__ void scan2_kernel(int* __restrict__ blockSums, int nb) {
    __shared__ int tmp[512];
    int t = threadIdx.x;
    int v = (t < nb) ? blockSums[t] : 0;
    tmp[t] = v;
    __syncthreads();
#pragma unroll
    for (int off = 1; off < 512; off <<= 1) {
        int add = (t >= off) ? tmp[t - off] : 0;
        __syncthreads();
        tmp[t] += add;
        __syncthreads();
    }
    if (t < nb) blockSums[t] = tmp[t] - v;
}

// ---------------- scan3 + scale_h1 fused: rowstart final add; h1 *= dinv ----------------
__global__ __launch_bounds__(256) void scan3_scale_kernel(
        int* __restrict__ rowstart, const int* __restrict__ blockSums,
        _Float16* __restrict__ h1, const float* __restrict__ dinv, int n) {
    int j = blockIdx.x * 256 + threadIdx.x;
    if (j < n) rowstart[j] += blockSums[j >> 8];
    if (j < n * 16) {                      // one f16x8 (16B) per thread
        float dv = dinv[j >> 4];
        f16x8 v = ((const f16x8*)h1)[j];
#pragma unroll
        for (int k = 0; k < 8; k++) v[k] = (_Float16)((float)v[k] * dv);
        ((f16x8*)h1)[j] = v;
    }
}

// ---------------- fused: partition (8192-edge 2-pass, packed 4B, NO deg atomics) | GEMM1 ----------------
// 9-slot groups: 8 GEMM blocks + 1 sort block. Sort: phase A histograms dst
// (re-read from L2 in phase C), phase B claims ~42-entry chunks (full-line
// writes, no cross-XCD false sharing), phase C writes packed (d&511)<<17|src.
__global__ __launch_bounds__(256) void part_gemm1_kernel(
        const int* __restrict__ src, const int* __restrict__ dst,
        int* __restrict__ bktCnt, int* __restrict__ ovfCnt,
        int2* __restrict__ ovfBuf, unsigned* __restrict__ pairPart, int E,
        const float* __restrict__ x, const _Float16* __restrict__ Wt,
        _Float16* __restrict__ h, int n, int nbkt) {
    __shared__ union {
        _Float16 xs_h[64][128];   // 16 KB
        struct { int cnt[NBKT_MAX]; int gbase[NBKT_MAX]; int off[NBKT_MAX]; } s;
    } u;
    int bid = blockIdx.x;
    int t = threadIdx.x;
    if (bid % 9 != 8) {
        // ---- GEMM1: 64 nodes x 128 cols, mfma_f32_16x16x32_f16 ----
        int gb = (bid / 9) * 8 + (bid % 9);
        int node0 = gb * 64;
        if (node0 >= n) return;

        // stage x tile -> fp16 LDS, swizzled: byte_in_row = seg*16 ^ ((row&7)<<4)
#pragma unroll
        for (int i = 0; i < 4; i++) {
            int fi = t + 256 * i;           // 1024 slots of 8 halves
            int row = fi >> 4, seg = fi & 15;
            float4 a = make_float4(0.f, 0.f, 0.f, 0.f);
            float4 b4 = make_float4(0.f, 0.f, 0.f, 0.f);
            if (node0 + row < n) {
                const float4* xr = (const float4*)(x + (size_t)(node0 + row) * 128 + seg * 8);
                a = xr[0]; b4 = xr[1];
            }
            f16x8 hv;
            hv[0] = (_Float16)a.x;  hv[1] = (_Float16)a.y;
            hv[2] = (_Float16)a.z;  hv[3] = (_Float16)a.w;
            hv[4] = (_Float16)b4.x; hv[5] = (_Float16)b4.y;
            hv[6] = (_Float16)b4.z; hv[7] = (_Float16)b4.w;
            int byte = row * 256 + ((seg * 16) ^ ((row & 7) << 4));
            *(f16x8*)((char*)&u.xs_h[0][0] + byte) = hv;
        }
        __syncthreads();

        int wid = t >> 6, l = t & 63;
        int row0 = wid * 16;                 // wave's 16-row slice
        int arow = row0 + (l & 15);
        int kgrp = l >> 4;                   // 0..3
        f32x4 acc[8];
#pragma unroll
        for (int ct = 0; ct < 8; ct++) acc[ct] = (f32x4){0.f, 0.f, 0.f, 0.f};

        const char* xbase = (const char*)&u.xs_h[0][0] + arow * 256;
#pragma unroll
        for (int ks = 0; ks < 4; ks++) {
            int abyte = ((ks * 64 + kgrp * 16) ^ ((arow & 7) << 4));
            f16x8 afrag = *(const f16x8*)(xbase + abyte);
#pragma unroll
            for (int ct = 0; ct < 8; ct++) {
                f16x8 bfrag = *(const f16x8*)(Wt + (ct * 16 + (l & 15)) * 128 + ks * 32 + kgrp * 8);
                acc[ct] = __builtin_amdgcn_mfma_f32_16x16x32_f16(afrag, bfrag, acc[ct], 0, 0, 0);
            }
        }

        // epilogue: C/D row = (l>>4)*4 + reg, col = ct*16 + (l&15); raw fp16
        int r0 = row0 + kgrp * 4;
#pragma unroll
        for (int ct = 0; ct < 8; ct++) {
            int col = ct * 16 + (l & 15);
#pragma unroll
            for (int r = 0; r < 4; r++) {
                int node = node0 + r0 + r;
                if (node < n)
                    h[(size_t)node * 128 + col] = (_Float16)acc[ct][r];
            }
        }
    } else {
        // ---- partition: one 8192-edge tile per block, two passes over dst ----
        int sb = bid / 9;
        int base = sb * 8192;
        if (base >= E) return;
        int eend = base + 8192; if (eend > E) eend = E;
        // phase A: histogram (dst streamed, stays in L2 for phase C)
        for (int i = t; i < nbkt; i += 256) u.s.cnt[i] = 0;
        __syncthreads();
        for (int e = base + t; e < eend; e += 256)
            atomicAdd(&u.s.cnt[dst[e] >> 9], 1);
        __syncthreads();
        // phase B: claim contiguous chunks (avg ~42 entries = ~3 full lines)
        for (int i = t; i < nbkt; i += 256) {
            u.s.off[i] = 0;
            int c = u.s.cnt[i];
            if (c > 0) u.s.gbase[i] = atomicAdd(&bktCnt[i], c);
        }
        __syncthreads();
        // phase C: packed scatter into claimed chunks
        for (int e = base + t; e < eend; e += 256) {
            int s = src[e], d = dst[e];
            int b = d >> 9;
            int slot = u.s.gbase[b] + atomicAdd(&u.s.off[b], 1);
            unsigned p = ((unsigned)(d & 511) << 17) | (unsigned)s;
            if (slot < BKT_CAP) {
                pairPart[(size_t)b * BKT_CAP + slot] = p;
            } else {
                int op = atomicAdd(ovfCnt, 1);       // statistically never taken
                if (op < OVF_CAP) ovfBuf[op] = make_int2((int)p, b);
            }
        }
    }
}

// ---------------- deg from buckets: LDS histogram, coalesced deg write ----------------
__global__ __launch_bounds__(256) void deg_bucket_kernel(
        const unsigned* __restrict__ pairPart, const int* __restrict__ bktCnt,
        const int* __restrict__ ovfCnt, const int2* __restrict__ ovfBuf,
        int* __restrict__ deg, int n) {
    __shared__ int hist[512];
    int b = blockIdx.x;
    int t = threadIdx.x;
    hist[t] = 0; hist[t + 256] = 0;
    __syncthreads();
    int cnt = bktCnt[b];
    if (cnt > BKT_CAP) cnt = BKT_CAP;
    const unsigned* bp = pairPart + (size_t)b * BKT_CAP;
    for (int e = t; e < cnt; e += 256)
        atomicAdd(&hist[bp[e] >> 17], 1);
    int oc = *ovfCnt;
    if (oc > 0) {
        if (oc > OVF_CAP) oc = OVF_CAP;
        for (int i = t; i < oc; i += 256) {
            int2 p = ovfBuf[i];
            if (p.y == b) atomicAdd(&hist[((unsigned)p.x) >> 17], 1);
        }
    }
    __syncthreads();
    int node0 = b << 9;
    if (node0 + t < n)       deg[node0 + t]       = hist[t];
    if (node0 + t + 256 < n) deg[node0 + t + 256] = hist[t + 256];
}

// ---------------- pass 2: exact-dst scatter within one bucket per block ----------------
__global__ __launch_bounds__(256) void scatter2_kernel(
        const unsigned* __restrict__ pairPart, const int* __restrict__ bktCnt,
        const int* __restrict__ ovfCnt, const int2* __restrict__ ovfBuf,
        const int* __restrict__ rowstart,
        int* __restrict__ srcSorted, int n) {
    __shared__ int lcur[512];
    int b = blockIdx.x;
    int t = threadIdx.x;
    int node0 = b << 9;
#pragma unroll
    for (int i = 0; i < 2; i++) {
        int node = node0 + t + 256 * i;
        if (node < n) lcur[t + 256 * i] = rowstart[node];
    }
    __syncthreads();
    int cnt = bktCnt[b];
    if (cnt > BKT_CAP) cnt = BKT_CAP;
    const unsigned* bp = pairPart + (size_t)b * BKT_CAP;
    for (int e = t; e < cnt; e += 256) {
        unsigned p = bp[e];
        int pos = atomicAdd(&lcur[p >> 17], 1);
        srcSorted[pos] = (int)(p & SRC_MASK);
    }
    int oc = *ovfCnt;
    if (oc > 0) {               // overflow drain (expected 0 iterations)
        if (oc > OVF_CAP) oc = OVF_CAP;
        for (int i = t; i < oc; i += 256) {
            int2 p = ovfBuf[i];
            if (p.y == b) {
                int pos = atomicAdd(&lcur[((unsigned)p.x) >> 17], 1);
                srcSorted[pos] = (int)((unsigned)p.x & SRC_MASK);
            }
        }
    }
}

// ---------------- gather1: h2 = relu(dg * agg(h1') + b1)  [proven R4 shape] ----------------
__global__ __launch_bounds__(256) void gather1_kernel(
        const int* __restrict__ srcS, const int* __restrict__ rowstart,
        const int* __restrict__ deg, const float* __restrict__ dinv,
        const _Float16* __restrict__ h1, const float* __restrict__ b1,
        float* __restrict__ h2, int n) {
    int t = threadIdx.x;
    int g = __builtin_amdgcn_readfirstlane(blockIdx.x * 4 + (t >> 6));
    int lane = t & 63;
    if (g >= n) return;

    float dg = dinv[g];
    half2v sv0 = ((const half2v*)(h1 + (size_t)g * 128))[lane];  // self term (pre-scaled)
    float2 acc = make_float2((float)sv0.x, (float)sv0.y);
    int beg = rowstart[g], end = beg + deg[g];
    int e = beg;
    while (e < end) {
        int rem = end - e;
        int sv = (lane < rem) ? srcS[e + lane] : 0;   // 1 coalesced load / 64 edges
        int chunk = rem < 64 ? rem : 64;
        int j = 0;
        for (; j + 8 <= chunk; j += 8) {
            int s0 = __shfl(sv, j + 0), s1 = __shfl(sv, j + 1);
            int s2 = __shfl(sv, j + 2), s3 = __shfl(sv, j + 3);
            int s4 = __shfl(sv, j + 4), s5 = __shfl(sv, j + 5);
            int s6 = __shfl(sv, j + 6), s7 = __shfl(sv, j + 7);
            half2v u0 = ((const half2v*)(h1 + (size_t)s0 * 128))[lane];
            half2v u1 = ((const half2v*)(h1 + (size_t)s1 * 128))[lane];
            half2v u2 = ((const half2v*)(h1 + (size_t)s2 * 128))[lane];
            half2v u3 = ((const half2v*)(h1 + (size_t)s3 * 128))[lane];
            half2v u4 = ((const half2v*)(h1 + (size_t)s4 * 128))[lane];
            half2v u5 = ((const half2v*)(h1 + (size_t)s5 * 128))[lane];
            half2v u6 = ((const half2v*)(h1 + (size_t)s6 * 128))[lane];
            half2v u7 = ((const half2v*)(h1 + (size_t)s7 * 128))[lane];
            acc.x += (float)u0.x; acc.y += (float)u0.y;
            acc.x += (float)u1.x; acc.y += (float)u1.y;
            acc.x += (float)u2.x; acc.y += (float)u2.y;
            acc.x += (float)u3.x; acc.y += (float)u3.y;
            acc.x += (float)u4.x; acc.y += (float)u4.y;
            acc.x += (float)u5.x; acc.y += (float)u5.y;
            acc.x += (float)u6.x; acc.y += (float)u6.y;
            acc.x += (float)u7.x; acc.y += (float)u7.y;
        }
        for (; j < chunk; j++) {
            int s = __shfl(sv, j);
            half2v u = ((const half2v*)(h1 + (size_t)s * 128))[lane];
            acc.x += (float)u.x; acc.y += (float)u.y;
        }
        e += chunk;
    }
    float2 b = ((const float2*)b1)[lane];
    acc.x = fmaxf(dg * acc.x + b.x, 0.f);
    acc.y = fmaxf(dg * acc.y + b.y, 0.f);
    ((float2*)(h2 + (size_t)g * 128))[lane] = acc;
}

// ---------------- GEMM2: h3'[N,64] = fp16( dinv * (h2[N,128] @ W2[128,64]) ) ----------------
__global__ __launch_bounds__(256) void gemm_nk64(const float* __restrict__ x,
                                                 const float* __restrict__ W,
                                                 const float* __restrict__ dinv,
                                                 _Float16* __restrict__ h, int n) {
    __shared__ float xs[32][128];
    int t = threadIdx.x;
    int node0 = blockIdx.x * 32;
#pragma unroll
    for (int i = 0; i < 4; i++) {
        int fi = t + 256 * i;
        int row = fi >> 5, cv = fi & 31;
        float4 v = make_float4(0.f, 0.f, 0.f, 0.f);
        if (node0 + row < n) v = ((const float4*)x)[(size_t)(node0 + row) * 32 + cv];
        ((float4*)(&xs[0][0]))[fi] = v;
    }
    __syncthreads();

    int tx = t & 15, ty = t >> 4;
    int c0 = tx * 4;
    float acc[2][4];
#pragma unroll
    for (int i = 0; i < 2; i++)
#pragma unroll
        for (int j = 0; j < 4; j++) acc[i][j] = 0.f;

    for (int k = 0; k < 128; k++) {
        float4 w = *(const float4*)(W + k * 64 + c0);
#pragma unroll
        for (int i = 0; i < 2; i++) {
            float xval = xs[ty + 16 * i][k];
            acc[i][0] += xval * w.x;
            acc[i][1] += xval * w.y;
            acc[i][2] += xval * w.z;
            acc[i][3] += xval * w.w;
        }
    }
#pragma unroll
    for (int i = 0; i < 2; i++) {
        int node = node0 + ty + 16 * i;
        if (node < n) {
            float dv = dinv[node];
            half4v hv;
            hv.x = (_Float16)(acc[i][0] * dv);
            hv.y = (_Float16)(acc[i][1] * dv);
            hv.z = (_Float16)(acc[i][2] * dv);
            hv.w = (_Float16)(acc[i][3] * dv);
            *(half4v*)(h + (size_t)node * 64 + c0) = hv;
        }
    }
}

// ---------------- gather2: out = dg * agg(h3') + b2 ----------------
__global__ __launch_bounds__(256) void gather2_kernel(
        const int* __restrict__ srcS, const int* __restrict__ rowstart,
        const int* __restrict__ deg, const float* __restrict__ dinv,
        const _Float16* __restrict__ h3, const float* __restrict__ b2,
        float* __restrict__ out, int n) {
    int t = threadIdx.x;
    int g = __builtin_amdgcn_readfirstlane(blockIdx.x * 4 + (t >> 6));
    int lane = t & 63;
    if (g >= n) return;
    float dg = dinv[g];
    float acc = (float)h3[(size_t)g * 64 + lane];   // self term (pre-scaled)
    int beg = rowstart[g], end = beg + deg[g];
    int e = beg;
    while (e < end) {
        int rem = end - e;
        int sv = (lane < rem) ? srcS[e + lane] : 0;
        int chunk = rem < 64 ? rem : 64;
        int j = 0;
        for (; j + 8 <= chunk; j += 8) {
            int s0 = __shfl(sv, j + 0), s1 = __shfl(sv, j + 1);
            int s2 = __shfl(sv, j + 2), s3 = __shfl(sv, j + 3);
            int s4 = __shfl(sv, j + 4), s5 = __shfl(sv, j + 5);
            int s6 = __shfl(sv, j + 6), s7 = __shfl(sv, j + 7);
            float u0 = (float)h3[(size_t)s0 * 64 + lane];
            float u1 = (float)h3[(size_t)s1 * 64 + lane];
            float u2 = (float)h3[(size_t)s2 * 64 + lane];
            float u3 = (float)h3[(size_t)s3 * 64 + lane];
            float u4 = (float)h3[(size_t)s4 * 64 + lane];
            float u5 = (float)h3[(size_t)s5 * 64 + lane];
            float u6 = (float)h3[(size_t)s6 * 64 + lane];
            float u7 = (float)h3[(size_t)s7 * 64 + lane];
            acc += u0 + u1 + u2 + u3 + u4 + u5 + u6 + u7;
        }
        for (; j < chunk; j++) {
            int s = __shfl(sv, j);
            acc += (float)h3[(size_t)s * 64 + lane];
        }
        e += chunk;
    }
    out[(size_t)g * 64 + lane] = dg * acc + b2[lane];
}

extern "C" void kernel_launch(void* const* d_in, const int* in_sizes, int n_in,
                              void* d_out, int out_size, void* d_ws, size_t ws_size,
                              hipStream_t stream) {
    const float* x  = (const float*)d_in[0];
    const int*   ei = (const int*)d_in[1];
    const float* W1 = (const float*)d_in[2];
    const float* b1 = (const float*)d_in[3];
    const float* W2 = (const float*)d_in[4];
    const float* b2 = (const float*)d_in[5];
    float* out = (float*)d_out;

    const int n = in_sizes[0] / 128;   // 100000
    const int E = in_sizes[1] / 2;     // 1600000
    const int* src = ei;
    const int* dst = ei + E;
    const int nb = (n + 255) / 256;
    const int nbkt = (n + 511) >> 9;   // 196 coarse buckets (512 nodes each)

    char* ws = (char*)d_ws;
    size_t off = 0;
    auto carve = [&](size_t bytes) -> char* {
        char* p = ws + off;
        off += (bytes + 255) & ~(size_t)255;
        return p;
    };
    // bktCnt/ovfCnt contiguous -> single small memset
    int*   bktCnt    = (int*)carve((size_t)NBKT_MAX * 4);
    int*   ovfCnt    = (int*)carve(4);
    size_t msz       = (size_t)((char*)ovfCnt - (char*)bktCnt) + 256;
    int*   deg       = (int*)carve((size_t)n * 4);       // fully overwritten by deg_bucket
    float* dinv      = (float*)carve((size_t)n * 4);
    int*   rowstart  = (int*)carve((size_t)n * 4);
    int*   blockSums = (int*)carve((size_t)nb * 4);
    int*   srcSorted = (int*)carve((size_t)E * 4);
    _Float16* Wt     = (_Float16*)carve((size_t)128 * 128 * 2);    // W1^T fp16
    int2*  ovfBuf    = (int2*)carve((size_t)OVF_CAP * 8);
    _Float16* h1     = (_Float16*)carve((size_t)n * 128 * 2);      // x@W1 fp16 (scaled in-place); then h3
    float* bufB      = (float*)carve((size_t)n * 128 * 4);         // pairPart (pass1-2), then h2
    unsigned* pairPart = (unsigned*)bufB;  // 12.8MB <= 51.2MB, dead before gather1 writes h2
    _Float16* h3     = h1;                 // gemm_nk64 writes after gather1 finishes reading h1

    hipMemsetAsync(bktCnt, 0, msz, stream);

    wcast_kernel<<<64, 256, 0, stream>>>(W1, Wt);

    // fused partition | gemm1 (8 GEMM : 1 sort per 9-group)
    int sortBlocks = (E + 8191) / 8192;             // 196
    int gemmBlocks = (n + 63) / 64;                 // 1563
    int gGroups = (gemmBlocks + 7) / 8;             // 196
    int groups = (sortBlocks > gGroups) ? sortBlocks : gGroups;
    int G = groups * 9;
    part_gemm1_kernel<<<G, 256, 0, stream>>>(src, dst, bktCnt, ovfCnt, ovfBuf,
                                             pairPart, E, x, Wt, h1, n, nbkt);

    // deg from buckets (LDS histograms, coalesced writes)
    deg_bucket_kernel<<<nbkt, 256, 0, stream>>>(pairPart, bktCnt, ovfCnt, ovfBuf, deg, n);

    scan1_kernel<<<nb, 256, 0, stream>>>(deg, rowstart, blockSums, dinv, n);
    scan2_kernel<<<1, 512, 0, stream>>>(blockSums, nb);
    // rowstart final add + h1 *= dinv (fused)
    scan3_scale_kernel<<<(n * 16 + 255) / 256, 256, 0, stream>>>(rowstart, blockSums, h1, dinv, n);

    // exact scatter within buckets
    scatter2_kernel<<<nbkt, 256, 0, stream>>>(pairPart, bktCnt, ovfCnt, ovfBuf,
                                              rowstart, srcSorted, n);

    // layer 1 aggregation: h2 = relu(dg * agg(h1') + b1)
    gather1_kernel<<<(n + 3) / 4, 256, 0, stream>>>(srcSorted, rowstart, deg, dinv,
                                                    h1, b1, bufB, n);

    // layer 2: h3' = fp16(dinv * (h2@W2)) (reuses h1 buffer) ; out = dg * agg(h3') + b2
    gemm_nk64<<<(n + 31) / 32, 256, 0, stream>>>(bufB, W2, dinv, h3, n);
    gather2_kernel<<<(n + 3) / 4, 256, 0, stream>>>(srcSorted, rowstart, deg, dinv,
                                                    h3, b2, out, n);
}

// Round 9
// 345.608 us; speedup vs baseline: 1.1898x; 1.0664x over previous
//
#include <hip/hip_runtime.h>

typedef _Float16 half2v __attribute__((ext_vector_type(2)));
typedef _Float16 half4v __attribute__((ext_vector_type(4)));
typedef _Float16 f16x8 __attribute__((ext_vector_type(8)));
typedef float f32x4 __attribute__((ext_vector_type(4)));

#define NBKT_MAX 256     // n<=131072 with 512-node buckets
#define BKT_CAP  16384   // per-bucket pair capacity (mean 8163, sigma~90 -> +91 sigma)
#define OVF_CAP  8192    // overflow list capacity (expected use: 0)
#define SRC_MASK 0x1FFFF // 17-bit src (n < 131072)

// ---------------- W1 cast + transpose: Wt[col][k] fp16 ----------------
__global__ void wcast_kernel(const float* __restrict__ W, _Float16* __restrict__ Wt) {
    int t = blockIdx.x * 256 + threadIdx.x;
    if (t < 128 * 128) {
        int k = t >> 7, c = t & 127;
        Wt[c * 128 + k] = (_Float16)W[k * 128 + c];
    }
}

// ---------------- scan1 (+ fused dinv) ----------------
__global__ void scan1_kernel(const int* __restrict__ deg, int* __restrict__ rowstart,
                             int* __restrict__ blockSums, float* __restrict__ dinv, int n) {
    __shared__ int tmp[256];
    int t = threadIdx.x;
    int i = blockIdx.x * 256 + t;
    int v = (i < n) ? deg[i] : 0;
    if (i < n) dinv[i] = rsqrtf((float)(v + 1));  // +1 = self loop
    tmp[t] = v;
    __syncthreads();
#pragma unroll
    for (int off = 1; off < 256; off <<= 1) {
        int add = (t >= off) ? tmp[t - off] : 0;
        __syncthreads();
        tmp[t] += add;
        __syncthreads();
    }
    if (i < n) rowstart[i] = tmp[t] - v;
    if (t == 255) blockSums[blockIdx.x] = tmp[255];
}

__global__ void scan2_kernel(int* __restrict__ blockSums, int nb) {
    __shared__ int tmp[512];
    int t = threadIdx.x;
    int v = (t < nb) ? blockSums[t] : 0;
    tmp[t] = v;
    __syncthreads();
#pragma unroll
    for (int off = 1; off < 512; off <<= 1) {
        int add = (t >= off) ? tmp[t - off] : 0;
        __syncthreads();
        tmp[t] += add;
        __syncthreads();
    }
    if (t < nb) blockSums[t] = tmp[t] - v;
}

// ---------------- scan3 + scale_h1 fused: rowstart final add; h1 *= dinv ----------------
__global__ __launch_bounds__(256) void scan3_scale_kernel(
        int* __restrict__ rowstart, const int* __restrict__ blockSums,
        _Float16* __restrict__ h1, const float* __restrict__ dinv, int n) {
    int j = blockIdx.x * 256 + threadIdx.x;
    if (j < n) rowstart[j] += blockSums[j >> 8];
    if (j < n * 16) {                      // one f16x8 (16B) per thread
        float dv = dinv[j >> 4];
        f16x8 v = ((const f16x8*)h1)[j];
#pragma unroll
        for (int k = 0; k < 8; k++) v[k] = (_Float16)((float)v[k] * dv);
        ((f16x8*)h1)[j] = v;
    }
}

// ---------------- fused: partition (4096-edge 2-pass, int4-batched, packed 4B) | GEMM1 ----------------
// 5-slot groups: 4 GEMM + 1 sort. Sort: 8 edges/thread per sweep via int4
// pair-loads -> serial latency depth 2 (was 32). No per-edge global atomics.
__global__ __launch_bounds__(256) void part_gemm1_kernel(
        const int* __restrict__ src, const int* __restrict__ dst,
        int* __restrict__ bktCnt, int* __restrict__ ovfCnt,
        int2* __restrict__ ovfBuf, unsigned* __restrict__ pairPart, int E,
        const float* __restrict__ x, const _Float16* __restrict__ Wt,
        _Float16* __restrict__ h, int n, int nbkt) {
    __shared__ union {
        _Float16 xs_h[64][128];   // 16 KB
        struct { int cnt[NBKT_MAX]; int gbase[NBKT_MAX]; int off[NBKT_MAX]; } s;
    } u;
    int bid = blockIdx.x;
    int t = threadIdx.x;
    if (bid % 5 != 4) {
        // ---- GEMM1: 64 nodes x 128 cols, mfma_f32_16x16x32_f16 ----
        int gb = (bid / 5) * 4 + (bid % 5);
        int node0 = gb * 64;
        if (node0 >= n) return;

        // stage x tile -> fp16 LDS, swizzled: byte_in_row = seg*16 ^ ((row&7)<<4)
#pragma unroll
        for (int i = 0; i < 4; i++) {
            int fi = t + 256 * i;           // 1024 slots of 8 halves
            int row = fi >> 4, seg = fi & 15;
            float4 a = make_float4(0.f, 0.f, 0.f, 0.f);
            float4 b4 = make_float4(0.f, 0.f, 0.f, 0.f);
            if (node0 + row < n) {
                const float4* xr = (const float4*)(x + (size_t)(node0 + row) * 128 + seg * 8);
                a = xr[0]; b4 = xr[1];
            }
            f16x8 hv;
            hv[0] = (_Float16)a.x;  hv[1] = (_Float16)a.y;
            hv[2] = (_Float16)a.z;  hv[3] = (_Float16)a.w;
            hv[4] = (_Float16)b4.x; hv[5] = (_Float16)b4.y;
            hv[6] = (_Float16)b4.z; hv[7] = (_Float16)b4.w;
            int byte = row * 256 + ((seg * 16) ^ ((row & 7) << 4));
            *(f16x8*)((char*)&u.xs_h[0][0] + byte) = hv;
        }
        __syncthreads();

        int wid = t >> 6, l = t & 63;
        int row0 = wid * 16;                 // wave's 16-row slice
        int arow = row0 + (l & 15);
        int kgrp = l >> 4;                   // 0..3
        f32x4 acc[8];
#pragma unroll
        for (int ct = 0; ct < 8; ct++) acc[ct] = (f32x4){0.f, 0.f, 0.f, 0.f};

        const char* xbase = (const char*)&u.xs_h[0][0] + arow * 256;
#pragma unroll
        for (int ks = 0; ks < 4; ks++) {
            int abyte = ((ks * 64 + kgrp * 16) ^ ((arow & 7) << 4));
            f16x8 afrag = *(const f16x8*)(xbase + abyte);
#pragma unroll
            for (int ct = 0; ct < 8; ct++) {
                f16x8 bfrag = *(const f16x8*)(Wt + (ct * 16 + (l & 15)) * 128 + ks * 32 + kgrp * 8);
                acc[ct] = __builtin_amdgcn_mfma_f32_16x16x32_f16(afrag, bfrag, acc[ct], 0, 0, 0);
            }
        }

        // epilogue: C/D row = (l>>4)*4 + reg, col = ct*16 + (l&15); raw fp16
        int r0 = row0 + kgrp * 4;
#pragma unroll
        for (int ct = 0; ct < 8; ct++) {
            int col = ct * 16 + (l & 15);
#pragma unroll
            for (int r = 0; r < 4; r++) {
                int node = node0 + r0 + r;
                if (node < n)
                    h[(size_t)node * 128 + col] = (_Float16)acc[ct][r];
            }
        }
    } else {
        // ---- partition: one 4096-edge tile per block, 8-edge int4 batches ----
        int sb = bid / 5;
        int base = sb * 4096;
        if (base >= E) return;
        int eend = base + 4096; if (eend > E) eend = E;
        for (int i = t; i < nbkt; i += 256) u.s.cnt[i] = 0;
        __syncthreads();
        // phase A: histogram (8 dst per thread per sweep, 2 int4 loads)
        for (int e0 = base + t * 8; e0 < eend; e0 += 2048) {
            if (e0 + 8 <= eend) {
                int4 d0 = *(const int4*)(dst + e0);
                int4 d1 = *(const int4*)(dst + e0 + 4);
                atomicAdd(&u.s.cnt[d0.x >> 9], 1); atomicAdd(&u.s.cnt[d0.y >> 9], 1);
                atomicAdd(&u.s.cnt[d0.z >> 9], 1); atomicAdd(&u.s.cnt[d0.w >> 9], 1);
                atomicAdd(&u.s.cnt[d1.x >> 9], 1); atomicAdd(&u.s.cnt[d1.y >> 9], 1);
                atomicAdd(&u.s.cnt[d1.z >> 9], 1); atomicAdd(&u.s.cnt[d1.w >> 9], 1);
            } else {
                for (int e = e0; e < eend; e++) atomicAdd(&u.s.cnt[dst[e] >> 9], 1);
            }
        }
        __syncthreads();
        // phase B: claim contiguous chunks
        for (int i = t; i < nbkt; i += 256) {
            u.s.off[i] = 0;
            int c = u.s.cnt[i];
            if (c > 0) u.s.gbase[i] = atomicAdd(&bktCnt[i], c);
        }
        __syncthreads();
        // phase C: packed scatter (8 edges per thread per sweep)
        for (int e0 = base + t * 8; e0 < eend; e0 += 2048) {
            if (e0 + 8 <= eend) {
                int4 s0 = *(const int4*)(src + e0);
                int4 s1 = *(const int4*)(src + e0 + 4);
                int4 d0 = *(const int4*)(dst + e0);
                int4 d1 = *(const int4*)(dst + e0 + 4);
                int ss[8] = {s0.x, s0.y, s0.z, s0.w, s1.x, s1.y, s1.z, s1.w};
                int dd[8] = {d0.x, d0.y, d0.z, d0.w, d1.x, d1.y, d1.z, d1.w};
#pragma unroll
                for (int j = 0; j < 8; j++) {
                    int b = dd[j] >> 9;
                    int slot = u.s.gbase[b] + atomicAdd(&u.s.off[b], 1);
                    unsigned p = ((unsigned)(dd[j] & 511) << 17) | (unsigned)ss[j];
                    if (slot < BKT_CAP) {
                        pairPart[(size_t)b * BKT_CAP + slot] = p;
                    } else {
                        int op = atomicAdd(ovfCnt, 1);
                        if (op < OVF_CAP) ovfBuf[op] = make_int2((int)p, b);
                    }
                }
            } else {
                for (int e = e0; e < eend; e++) {
                    int s = src[e], d = dst[e];
                    int b = d >> 9;
                    int slot = u.s.gbase[b] + atomicAdd(&u.s.off[b], 1);
                    unsigned p = ((unsigned)(d & 511) << 17) | (unsigned)s;
                    if (slot < BKT_CAP) {
                        pairPart[(size_t)b * BKT_CAP + slot] = p;
                    } else {
                        int op = atomicAdd(ovfCnt, 1);
                        if (op < OVF_CAP) ovfBuf[op] = make_int2((int)p, b);
                    }
                }
            }
        }
    }
}

// ---------------- deg from buckets: LDS histogram (4-batched), coalesced deg write ----------------
__global__ __launch_bounds__(256) void deg_bucket_kernel(
        const unsigned* __restrict__ pairPart, const int* __restrict__ bktCnt,
        const int* __restrict__ ovfCnt, const int2* __restrict__ ovfBuf,
        int* __restrict__ deg, int n) {
    __shared__ int hist[512];
    int b = blockIdx.x;
    int t = threadIdx.x;
    hist[t] = 0; hist[t + 256] = 0;
    __syncthreads();
    int cnt = bktCnt[b];
    if (cnt > BKT_CAP) cnt = BKT_CAP;
    const unsigned* bp = pairPart + (size_t)b * BKT_CAP;
    for (int e0 = t * 4; e0 < cnt; e0 += 1024) {
        if (e0 + 4 <= cnt) {
            uint4 p = *(const uint4*)(bp + e0);
            atomicAdd(&hist[p.x >> 17], 1); atomicAdd(&hist[p.y >> 17], 1);
            atomicAdd(&hist[p.z >> 17], 1); atomicAdd(&hist[p.w >> 17], 1);
        } else {
            for (int e = e0; e < cnt; e++) atomicAdd(&hist[bp[e] >> 17], 1);
        }
    }
    int oc = *ovfCnt;
    if (oc > 0) {
        if (oc > OVF_CAP) oc = OVF_CAP;
        for (int i = t; i < oc; i += 256) {
            int2 p = ovfBuf[i];
            if (p.y == b) atomicAdd(&hist[((unsigned)p.x) >> 17], 1);
        }
    }
    __syncthreads();
    int node0 = b << 9;
    if (node0 + t < n)       deg[node0 + t]       = hist[t];
    if (node0 + t + 256 < n) deg[node0 + t + 256] = hist[t + 256];
}

// ---------------- pass 2: exact-dst scatter within one bucket per block (4-batched) ----------------
__global__ __launch_bounds__(256) void scatter2_kernel(
        const unsigned* __restrict__ pairPart, const int* __restrict__ bktCnt,
        const int* __restrict__ ovfCnt, const int2* __restrict__ ovfBuf,
        const int* __restrict__ rowstart,
        int* __restrict__ srcSorted, int n) {
    __shared__ int lcur[512];
    int b = blockIdx.x;
    int t = threadIdx.x;
    int node0 = b << 9;
#pragma unroll
    for (int i = 0; i < 2; i++) {
        int node = node0 + t + 256 * i;
        if (node < n) lcur[t + 256 * i] = rowstart[node];
    }
    __syncthreads();
    int cnt = bktCnt[b];
    if (cnt > BKT_CAP) cnt = BKT_CAP;
    const unsigned* bp = pairPart + (size_t)b * BKT_CAP;
    for (int e0 = t * 4; e0 < cnt; e0 += 1024) {
        if (e0 + 4 <= cnt) {
            uint4 p = *(const uint4*)(bp + e0);
            int p0 = atomicAdd(&lcur[p.x >> 17], 1);
            int p1 = atomicAdd(&lcur[p.y >> 17], 1);
            int p2 = atomicAdd(&lcur[p.z >> 17], 1);
            int p3 = atomicAdd(&lcur[p.w >> 17], 1);
            srcSorted[p0] = (int)(p.x & SRC_MASK);
            srcSorted[p1] = (int)(p.y & SRC_MASK);
            srcSorted[p2] = (int)(p.z & SRC_MASK);
            srcSorted[p3] = (int)(p.w & SRC_MASK);
        } else {
            for (int e = e0; e < cnt; e++) {
                unsigned p = bp[e];
                int pos = atomicAdd(&lcur[p >> 17], 1);
                srcSorted[pos] = (int)(p & SRC_MASK);
            }
        }
    }
    int oc = *ovfCnt;
    if (oc > 0) {               // overflow drain (expected 0 iterations)
        if (oc > OVF_CAP) oc = OVF_CAP;
        for (int i = t; i < oc; i += 256) {
            int2 p = ovfBuf[i];
            if (p.y == b) {
                int pos = atomicAdd(&lcur[((unsigned)p.x) >> 17], 1);
                srcSorted[pos] = (int)((unsigned)p.x & SRC_MASK);
            }
        }
    }
}

// ---------------- gather1: h2 = relu(dg * agg(h1') + b1)  [proven R4 shape] ----------------
__global__ __launch_bounds__(256) void gather1_kernel(
        const int* __restrict__ srcS, const int* __restrict__ rowstart,
        const int* __restrict__ deg, const float* __restrict__ dinv,
        const _Float16* __restrict__ h1, const float* __restrict__ b1,
        float* __restrict__ h2, int n) {
    int t = threadIdx.x;
    int g = __builtin_amdgcn_readfirstlane(blockIdx.x * 4 + (t >> 6));
    int lane = t & 63;
    if (g >= n) return;

    float dg = dinv[g];
    half2v sv0 = ((const half2v*)(h1 + (size_t)g * 128))[lane];  // self term (pre-scaled)
    float2 acc = make_float2((float)sv0.x, (float)sv0.y);
    int beg = rowstart[g], end = beg + deg[g];
    int e = beg;
    while (e < end) {
        int rem = end - e;
        int sv = (lane < rem) ? srcS[e + lane] : 0;   // 1 coalesced load / 64 edges
        int chunk = rem < 64 ? rem : 64;
        int j = 0;
        for (; j + 8 <= chunk; j += 8) {
            int s0 = __shfl(sv, j + 0), s1 = __shfl(sv, j + 1);
            int s2 = __shfl(sv, j + 2), s3 = __shfl(sv, j + 3);
            int s4 = __shfl(sv, j + 4), s5 = __shfl(sv, j + 5);
            int s6 = __shfl(sv, j + 6), s7 = __shfl(sv, j + 7);
            half2v u0 = ((const half2v*)(h1 + (size_t)s0 * 128))[lane];
            half2v u1 = ((const half2v*)(h1 + (size_t)s1 * 128))[lane];
            half2v u2 = ((const half2v*)(h1 + (size_t)s2 * 128))[lane];
            half2v u3 = ((const half2v*)(h1 + (size_t)s3 * 128))[lane];
            half2v u4 = ((const half2v*)(h1 + (size_t)s4 * 128))[lane];
            half2v u5 = ((const half2v*)(h1 + (size_t)s5 * 128))[lane];
            half2v u6 = ((const half2v*)(h1 + (size_t)s6 * 128))[lane];
            half2v u7 = ((const half2v*)(h1 + (size_t)s7 * 128))[lane];
            acc.x += (float)u0.x; acc.y += (float)u0.y;
            acc.x += (float)u1.x; acc.y += (float)u1.y;
            acc.x += (float)u2.x; acc.y += (float)u2.y;
            acc.x += (float)u3.x; acc.y += (float)u3.y;
            acc.x += (float)u4.x; acc.y += (float)u4.y;
            acc.x += (float)u5.x; acc.y += (float)u5.y;
            acc.x += (float)u6.x; acc.y += (float)u6.y;
            acc.x += (float)u7.x; acc.y += (float)u7.y;
        }
        for (; j < chunk; j++) {
            int s = __shfl(sv, j);
            half2v u = ((const half2v*)(h1 + (size_t)s * 128))[lane];
            acc.x += (float)u.x; acc.y += (float)u.y;
        }
        e += chunk;
    }
    float2 b = ((const float2*)b1)[lane];
    acc.x = fmaxf(dg * acc.x + b.x, 0.f);
    acc.y = fmaxf(dg * acc.y + b.y, 0.f);
    ((float2*)(h2 + (size_t)g * 128))[lane] = acc;
}

// ---------------- GEMM2: h3'[N,64] = fp16( dinv * (h2[N,128] @ W2[128,64]) ) ----------------
__global__ __launch_bounds__(256) void gemm_nk64(const float* __restrict__ x,
                                                 const float* __restrict__ W,
                                                 const float* __restrict__ dinv,
                                                 _Float16* __restrict__ h, int n) {
    __shared__ float xs[32][128];
    int t = threadIdx.x;
    int node0 = blockIdx.x * 32;
#pragma unroll
    for (int i = 0; i < 4; i++) {
        int fi = t + 256 * i;
        int row = fi >> 5, cv = fi & 31;
        float4 v = make_float4(0.f, 0.f, 0.f, 0.f);
        if (node0 + row < n) v = ((const float4*)x)[(size_t)(node0 + row) * 32 + cv];
        ((float4*)(&xs[0][0]))[fi] = v;
    }
    __syncthreads();

    int tx = t & 15, ty = t >> 4;
    int c0 = tx * 4;
    float acc[2][4];
#pragma unroll
    for (int i = 0; i < 2; i++)
#pragma unroll
        for (int j = 0; j < 4; j++) acc[i][j] = 0.f;

    for (int k = 0; k < 128; k++) {
        float4 w = *(const float4*)(W + k * 64 + c0);
#pragma unroll
        for (int i = 0; i < 2; i++) {
            float xval = xs[ty + 16 * i][k];
            acc[i][0] += xval * w.x;
            acc[i][1] += xval * w.y;
            acc[i][2] += xval * w.z;
            acc[i][3] += xval * w.w;
        }
    }
#pragma unroll
    for (int i = 0; i < 2; i++) {
        int node = node0 + ty + 16 * i;
        if (node < n) {
            float dv = dinv[node];
            half4v hv;
            hv.x = (_Float16)(acc[i][0] * dv);
            hv.y = (_Float16)(acc[i][1] * dv);
            hv.z = (_Float16)(acc[i][2] * dv);
            hv.w = (_Float16)(acc[i][3] * dv);
            *(half4v*)(h + (size_t)node * 64 + c0) = hv;
        }
    }
}

// ---------------- gather2: out = dg * agg(h3') + b2 ----------------
__global__ __launch_bounds__(256) void gather2_kernel(
        const int* __restrict__ srcS, const int* __restrict__ rowstart,
        const int* __restrict__ deg, const float* __restrict__ dinv,
        const _Float16* __restrict__ h3, const float* __restrict__ b2,
        float* __restrict__ out, int n) {
    int t = threadIdx.x;
    int g = __builtin_amdgcn_readfirstlane(blockIdx.x * 4 + (t >> 6));
    int lane = t & 63;
    if (g >= n) return;
    float dg = dinv[g];
    float acc = (float)h3[(size_t)g * 64 + lane];   // self term (pre-scaled)
    int beg = rowstart[g], end = beg + deg[g];
    int e = beg;
    while (e < end) {
        int rem = end - e;
        int sv = (lane < rem) ? srcS[e + lane] : 0;
        int chunk = rem < 64 ? rem : 64;
        int j = 0;
        for (; j + 8 <= chunk; j += 8) {
            int s0 = __shfl(sv, j + 0), s1 = __shfl(sv, j + 1);
            int s2 = __shfl(sv, j + 2), s3 = __shfl(sv, j + 3);
            int s4 = __shfl(sv, j + 4), s5 = __shfl(sv, j + 5);
            int s6 = __shfl(sv, j + 6), s7 = __shfl(sv, j + 7);
            float u0 = (float)h3[(size_t)s0 * 64 + lane];
            float u1 = (float)h3[(size_t)s1 * 64 + lane];
            float u2 = (float)h3[(size_t)s2 * 64 + lane];
            float u3 = (float)h3[(size_t)s3 * 64 + lane];
            float u4 = (float)h3[(size_t)s4 * 64 + lane];
            float u5 = (float)h3[(size_t)s5 * 64 + lane];
            float u6 = (float)h3[(size_t)s6 * 64 + lane];
            float u7 = (float)h3[(size_t)s7 * 64 + lane];
            acc += u0 + u1 + u2 + u3 + u4 + u5 + u6 + u7;
        }
        for (; j < chunk; j++) {
            int s = __shfl(sv, j);
            acc += (float)h3[(size_t)s * 64 + lane];
        }
        e += chunk;
    }
    out[(size_t)g * 64 + lane] = dg * acc + b2[lane];
}

extern "C" void kernel_launch(void* const* d_in, const int* in_sizes, int n_in,
                              void* d_out, int out_size, void* d_ws, size_t ws_size,
                              hipStream_t stream) {
    const float* x  = (const float*)d_in[0];
    const int*   ei = (const int*)d_in[1];
    const float* W1 = (const float*)d_in[2];
    const float* b1 = (const float*)d_in[3];
    const float* W2 = (const float*)d_in[4];
    const float* b2 = (const float*)d_in[5];
    float* out = (float*)d_out;

    const int n = in_sizes[0] / 128;   // 100000
    const int E = in_sizes[1] / 2;     // 1600000
    const int* src = ei;
    const int* dst = ei + E;
    const int nb = (n + 255) / 256;
    const int nbkt = (n + 511) >> 9;   // 196 coarse buckets (512 nodes each)

    char* ws = (char*)d_ws;
    size_t off = 0;
    auto carve = [&](size_t bytes) -> char* {
        char* p = ws + off;
        off += (bytes + 255) & ~(size_t)255;
        return p;
    };
    // bktCnt/ovfCnt contiguous -> single small memset
    int*   bktCnt    = (int*)carve((size_t)NBKT_MAX * 4);
    int*   ovfCnt    = (int*)carve(4);
    size_t msz       = (size_t)((char*)ovfCnt - (char*)bktCnt) + 256;
    int*   deg       = (int*)carve((size_t)n * 4);       // fully overwritten by deg_bucket
    float* dinv      = (float*)carve((size_t)n * 4);
    int*   rowstart  = (int*)carve((size_t)n * 4);
    int*   blockSums = (int*)carve((size_t)nb * 4);
    int*   srcSorted = (int*)carve((size_t)E * 4);
    _Float16* Wt     = (_Float16*)carve((size_t)128 * 128 * 2);    // W1^T fp16
    int2*  ovfBuf    = (int2*)carve((size_t)OVF_CAP * 8);
    _Float16* h1     = (_Float16*)carve((size_t)n * 128 * 2);      // x@W1 fp16 (scaled in-place); then h3
    float* bufB      = (float*)carve((size_t)n * 128 * 4);         // pairPart (pass1-2), then h2
    unsigned* pairPart = (unsigned*)bufB;  // 12.8MB <= 51.2MB, dead before gather1 writes h2
    _Float16* h3     = h1;                 // gemm_nk64 writes after gather1 finishes reading h1

    hipMemsetAsync(bktCnt, 0, msz, stream);

    wcast_kernel<<<64, 256, 0, stream>>>(W1, Wt);

    // fused partition | gemm1 (4 GEMM : 1 sort per 5-group)
    int sortBlocks = (E + 4095) / 4096;             // 391
    int gemmBlocks = (n + 63) / 64;                 // 1563
    int gGroups = (gemmBlocks + 3) / 4;             // 391
    int groups = (sortBlocks > gGroups) ? sortBlocks : gGroups;
    int G = groups * 5;
    part_gemm1_kernel<<<G, 256, 0, stream>>>(src, dst, bktCnt, ovfCnt, ovfBuf,
                                             pairPart, E, x, Wt, h1, n, nbkt);

    // deg from buckets (LDS histograms, coalesced writes)
    deg_bucket_kernel<<<nbkt, 256, 0, stream>>>(pairPart, bktCnt, ovfCnt, ovfBuf, deg, n);

    scan1_kernel<<<nb, 256, 0, stream>>>(deg, rowstart, blockSums, dinv, n);
    scan2_kernel<<<1, 512, 0, stream>>>(blockSums, nb);
    // rowstart final add + h1 *= dinv (fused)
    scan3_scale_kernel<<<(n * 16 + 255) / 256, 256, 0, stream>>>(rowstart, blockSums, h1, dinv, n);

    // exact scatter within buckets
    scatter2_kernel<<<nbkt, 256, 0, stream>>>(pairPart, bktCnt, ovfCnt, ovfBuf,
                                              rowstart, srcSorted, n);

    // layer 1 aggregation: h2 = relu(dg * agg(h1') + b1)
    gather1_kernel<<<(n + 3) / 4, 256, 0, stream>>>(srcSorted, rowstart, deg, dinv,
                                                    h1, b1, bufB, n);

    // layer 2: h3' = fp16(dinv * (h2@W2)) (reuses h1 buffer) ; out = dg * agg(h3') + b2
    gemm_nk64<<<(n + 31) / 32, 256, 0, stream>>>(bufB, W2, dinv, h3, n);
    gather2_kernel<<<(n + 3) / 4, 256, 0, stream>>>(srcSorted, rowstart, deg, dinv,
                                                    h3, b2, out, n);
}

// Round 11
// 344.972 us; speedup vs baseline: 1.1920x; 1.0018x over previous
//
#include <hip/hip_runtime.h>

typedef _Float16 half2v __attribute__((ext_vector_type(2)));
typedef _Float16 half4v __attribute__((ext_vector_type(4)));
typedef _Float16 f16x8 __attribute__((ext_vector_type(8)));
typedef float f32x4 __attribute__((ext_vector_type(4)));

#define NBKT_MAX 256     // n<=131072 with 512-node buckets
#define BKT_CAP  16384   // per-bucket pair capacity (mean 8163, sigma~90 -> +91 sigma)
#define OVF_CAP  8192    // overflow list capacity (expected use: 0)
#define SRC_MASK 0x1FFFF // 17-bit src (n < 131072)

// ---------------- W1 cast + transpose: Wt[col][k] fp16 ----------------
__global__ void wcast_kernel(const float* __restrict__ W, _Float16* __restrict__ Wt) {
    int t = blockIdx.x * 256 + threadIdx.x;
    if (t < 128 * 128) {
        int k = t >> 7, c = t & 127;
        Wt[c * 128 + k] = (_Float16)W[k * 128 + c];
    }
}

// ---------------- fused: partition (4096-edge 2-pass, int4-batched, packed 4B) | GEMM1 ----------------
__global__ __launch_bounds__(256) void part_gemm1_kernel(
        const int* __restrict__ src, const int* __restrict__ dst,
        int* __restrict__ bktCnt, int* __restrict__ ovfCnt,
        int2* __restrict__ ovfBuf, unsigned* __restrict__ pairPart, int E,
        const float* __restrict__ x, const _Float16* __restrict__ Wt,
        _Float16* __restrict__ h, int n, int nbkt) {
    __shared__ union {
        _Float16 xs_h[64][128];   // 16 KB
        struct { int cnt[NBKT_MAX]; int gbase[NBKT_MAX]; int off[NBKT_MAX]; } s;
    } u;
    int bid = blockIdx.x;
    int t = threadIdx.x;
    if (bid % 5 != 4) {
        // ---- GEMM1: 64 nodes x 128 cols, mfma_f32_16x16x32_f16 ----
        int gb = (bid / 5) * 4 + (bid % 5);
        int node0 = gb * 64;
        if (node0 >= n) return;

        // stage x tile -> fp16 LDS, swizzled: byte_in_row = seg*16 ^ ((row&7)<<4)
#pragma unroll
        for (int i = 0; i < 4; i++) {
            int fi = t + 256 * i;           // 1024 slots of 8 halves
            int row = fi >> 4, seg = fi & 15;
            float4 a = make_float4(0.f, 0.f, 0.f, 0.f);
            float4 b4 = make_float4(0.f, 0.f, 0.f, 0.f);
            if (node0 + row < n) {
                const float4* xr = (const float4*)(x + (size_t)(node0 + row) * 128 + seg * 8);
                a = xr[0]; b4 = xr[1];
            }
            f16x8 hv;
            hv[0] = (_Float16)a.x;  hv[1] = (_Float16)a.y;
            hv[2] = (_Float16)a.z;  hv[3] = (_Float16)a.w;
            hv[4] = (_Float16)b4.x; hv[5] = (_Float16)b4.y;
            hv[6] = (_Float16)b4.z; hv[7] = (_Float16)b4.w;
            int byte = row * 256 + ((seg * 16) ^ ((row & 7) << 4));
            *(f16x8*)((char*)&u.xs_h[0][0] + byte) = hv;
        }
        __syncthreads();

        int wid = t >> 6, l = t & 63;
        int row0 = wid * 16;                 // wave's 16-row slice
        int arow = row0 + (l & 15);
        int kgrp = l >> 4;                   // 0..3
        f32x4 acc[8];
#pragma unroll
        for (int ct = 0; ct < 8; ct++) acc[ct] = (f32x4){0.f, 0.f, 0.f, 0.f};

        const char* xbase = (const char*)&u.xs_h[0][0] + arow * 256;
#pragma unroll
        for (int ks = 0; ks < 4; ks++) {
            int abyte = ((ks * 64 + kgrp * 16) ^ ((arow & 7) << 4));
            f16x8 afrag = *(const f16x8*)(xbase + abyte);
#pragma unroll
            for (int ct = 0; ct < 8; ct++) {
                f16x8 bfrag = *(const f16x8*)(Wt + (ct * 16 + (l & 15)) * 128 + ks * 32 + kgrp * 8);
                acc[ct] = __builtin_amdgcn_mfma_f32_16x16x32_f16(afrag, bfrag, acc[ct], 0, 0, 0);
            }
        }

        // epilogue: C/D row = (l>>4)*4 + reg, col = ct*16 + (l&15); raw fp16
        int r0 = row0 + kgrp * 4;
#pragma unroll
        for (int ct = 0; ct < 8; ct++) {
            int col = ct * 16 + (l & 15);
#pragma unroll
            for (int r = 0; r < 4; r++) {
                int node = node0 + r0 + r;
                if (node < n)
                    h[(size_t)node * 128 + col] = (_Float16)acc[ct][r];
            }
        }
    } else {
        // ---- partition: one 4096-edge tile per block, 8-edge int4 batches ----
        int sb = bid / 5;
        int base = sb * 4096;
        if (base >= E) return;
        int eend = base + 4096; if (eend > E) eend = E;
        for (int i = t; i < nbkt; i += 256) u.s.cnt[i] = 0;
        __syncthreads();
        // phase A: histogram (8 dst per thread per sweep, 2 int4 loads)
        for (int e0 = base + t * 8; e0 < eend; e0 += 2048) {
            if (e0 + 8 <= eend) {
                int4 d0 = *(const int4*)(dst + e0);
                int4 d1 = *(const int4*)(dst + e0 + 4);
                atomicAdd(&u.s.cnt[d0.x >> 9], 1); atomicAdd(&u.s.cnt[d0.y >> 9], 1);
                atomicAdd(&u.s.cnt[d0.z >> 9], 1); atomicAdd(&u.s.cnt[d0.w >> 9], 1);
                atomicAdd(&u.s.cnt[d1.x >> 9], 1); atomicAdd(&u.s.cnt[d1.y >> 9], 1);
                atomicAdd(&u.s.cnt[d1.z >> 9], 1); atomicAdd(&u.s.cnt[d1.w >> 9], 1);
            } else {
                for (int e = e0; e < eend; e++) atomicAdd(&u.s.cnt[dst[e] >> 9], 1);
            }
        }
        __syncthreads();
        // phase B: claim contiguous chunks
        for (int i = t; i < nbkt; i += 256) {
            u.s.off[i] = 0;
            int c = u.s.cnt[i];
            if (c > 0) u.s.gbase[i] = atomicAdd(&bktCnt[i], c);
        }
        __syncthreads();
        // phase C: packed scatter (8 edges per thread per sweep)
        for (int e0 = base + t * 8; e0 < eend; e0 += 2048) {
            if (e0 + 8 <= eend) {
                int4 s0 = *(const int4*)(src + e0);
                int4 s1 = *(const int4*)(src + e0 + 4);
                int4 d0 = *(const int4*)(dst + e0);
                int4 d1 = *(const int4*)(dst + e0 + 4);
                int ss[8] = {s0.x, s0.y, s0.z, s0.w, s1.x, s1.y, s1.z, s1.w};
                int dd[8] = {d0.x, d0.y, d0.z, d0.w, d1.x, d1.y, d1.z, d1.w};
#pragma unroll
                for (int j = 0; j < 8; j++) {
                    int b = dd[j] >> 9;
                    int slot = u.s.gbase[b] + atomicAdd(&u.s.off[b], 1);
                    unsigned p = ((unsigned)(dd[j] & 511) << 17) | (unsigned)ss[j];
                    if (slot < BKT_CAP) {
                        pairPart[(size_t)b * BKT_CAP + slot] = p;
                    } else {
                        int op = atomicAdd(ovfCnt, 1);
                        if (op < OVF_CAP) ovfBuf[op] = make_int2((int)p, b);
                    }
                }
            } else {
                for (int e = e0; e < eend; e++) {
                    int s = src[e], d = dst[e];
                    int b = d >> 9;
                    int slot = u.s.gbase[b] + atomicAdd(&u.s.off[b], 1);
                    unsigned p = ((unsigned)(d & 511) << 17) | (unsigned)s;
                    if (slot < BKT_CAP) {
                        pairPart[(size_t)b * BKT_CAP + slot] = p;
                    } else {
                        int op = atomicAdd(ovfCnt, 1);
                        if (op < OVF_CAP) ovfBuf[op] = make_int2((int)p, b);
                    }
                }
            }
        }
    }
}

// ---------------- deg + dinv + bucket-local rowstart (fused histogram+scan, 512 thr) ----------------
__global__ __launch_bounds__(512) void deg_scan_kernel(
        const unsigned* __restrict__ pairPart, const int* __restrict__ bktCnt,
        const int* __restrict__ ovfCnt, const int2* __restrict__ ovfBuf,
        int* __restrict__ deg, float* __restrict__ dinv, int* __restrict__ rowstart,
        int* __restrict__ blockSums, int n) {
    __shared__ int hist[512];
    int b = blockIdx.x;
    int t = threadIdx.x;
    hist[t] = 0;
    __syncthreads();
    int cnt = bktCnt[b];
    if (cnt > BKT_CAP) cnt = BKT_CAP;
    const unsigned* bp = pairPart + (size_t)b * BKT_CAP;
    for (int e0 = t * 4; e0 < cnt; e0 += 2048) {
        if (e0 + 4 <= cnt) {
            uint4 p = *(const uint4*)(bp + e0);
            atomicAdd(&hist[p.x >> 17], 1); atomicAdd(&hist[p.y >> 17], 1);
            atomicAdd(&hist[p.z >> 17], 1); atomicAdd(&hist[p.w >> 17], 1);
        } else {
            for (int e = e0; e < cnt; e++) atomicAdd(&hist[bp[e] >> 17], 1);
        }
    }
    int oc = *ovfCnt;
    if (oc > 0) {
        if (oc > OVF_CAP) oc = OVF_CAP;
        for (int i = t; i < oc; i += 512) {
            int2 p = ovfBuf[i];
            if (p.y == b) atomicAdd(&hist[((unsigned)p.x) >> 17], 1);
        }
    }
    __syncthreads();
    int v = hist[t];
#pragma unroll
    for (int off = 1; off < 512; off <<= 1) {
        int add = (t >= off) ? hist[t - off] : 0;
        __syncthreads();
        hist[t] += add;
        __syncthreads();
    }
    int node = (b << 9) + t;
    if (node < n) {
        deg[node] = v;
        dinv[node] = rsqrtf((float)(v + 1));   // +1 = self loop
        rowstart[node] = hist[t] - v;          // bucket-local
    }
    if (t == 511) blockSums[b] = hist[511];
}

__global__ void scan2_kernel(int* __restrict__ blockSums, int nb) {
    __shared__ int tmp[512];
    int t = threadIdx.x;
    int v = (t < nb) ? blockSums[t] : 0;
    tmp[t] = v;
    __syncthreads();
#pragma unroll
    for (int off = 1; off < 512; off <<= 1) {
        int add = (t >= off) ? tmp[t - off] : 0;
        __syncthreads();
        tmp[t] += add;
        __syncthreads();
    }
    if (t < nb) blockSums[t] = tmp[t] - v;
}

// ---------------- scan3 + scale_h1 fused: rowstart final add (bucket base); h1 *= dinv ----------------
__global__ __launch_bounds__(256) void scan3_scale_kernel(
        int* __restrict__ rowstart, const int* __restrict__ blockSums,
        _Float16* __restrict__ h1, const float* __restrict__ dinv, int n) {
    int j = blockIdx.x * 256 + threadIdx.x;
    if (j < n) rowstart[j] += blockSums[j >> 9];
    if (j < n * 16) {                      // one f16x8 (16B) per thread
        float dv = dinv[j >> 4];
        f16x8 v = ((const f16x8*)h1)[j];
#pragma unroll
        for (int k = 0; k < 8; k++) v[k] = (_Float16)((float)v[k] * dv);
        ((f16x8*)h1)[j] = v;
    }
}

// ---------------- pass 2: exact-dst scatter within one bucket per block (4-batched) ----------------
__global__ __launch_bounds__(256) void scatter2_kernel(
        const unsigned* __restrict__ pairPart, const int* __restrict__ bktCnt,
        const int* __restrict__ ovfCnt, const int2* __restrict__ ovfBuf,
        const int* __restrict__ rowstart,
        int* __restrict__ srcSorted, int n) {
    __shared__ int lcur[512];
    int b = blockIdx.x;
    int t = threadIdx.x;
    int node0 = b << 9;
#pragma unroll
    for (int i = 0; i < 2; i++) {
        int node = node0 + t + 256 * i;
        if (node < n) lcur[t + 256 * i] = rowstart[node];
    }
    __syncthreads();
    int cnt = bktCnt[b];
    if (cnt > BKT_CAP) cnt = BKT_CAP;
    const unsigned* bp = pairPart + (size_t)b * BKT_CAP;
    for (int e0 = t * 4; e0 < cnt; e0 += 1024) {
        if (e0 + 4 <= cnt) {
            uint4 p = *(const uint4*)(bp + e0);
            int p0 = atomicAdd(&lcur[p.x >> 17], 1);
            int p1 = atomicAdd(&lcur[p.y >> 17], 1);
            int p2 = atomicAdd(&lcur[p.z >> 17], 1);
            int p3 = atomicAdd(&lcur[p.w >> 17], 1);
            srcSorted[p0] = (int)(p.x & SRC_MASK);
            srcSorted[p1] = (int)(p.y & SRC_MASK);
            srcSorted[p2] = (int)(p.z & SRC_MASK);
            srcSorted[p3] = (int)(p.w & SRC_MASK);
        } else {
            for (int e = e0; e < cnt; e++) {
                unsigned p = bp[e];
                int pos = atomicAdd(&lcur[p >> 17], 1);
                srcSorted[pos] = (int)(p & SRC_MASK);
            }
        }
    }
    int oc = *ovfCnt;
    if (oc > 0) {               // overflow drain (expected 0 iterations)
        if (oc > OVF_CAP) oc = OVF_CAP;
        for (int i = t; i < oc; i += 256) {
            int2 p = ovfBuf[i];
            if (p.y == b) {
                int pos = atomicAdd(&lcur[((unsigned)p.x) >> 17], 1);
                srcSorted[pos] = (int)((unsigned)p.x & SRC_MASK);
            }
        }
    }
}

// ---------------- gather1: h2 = relu(dg * agg(h1') + b1) ----------------
// 2 edges per VMEM instr: lanes 0-31 = edge A, lanes 32-63 = edge B; each lane
// loads half4 (4 cols). Partial sums combine via shfl_xor(32).
// NOTE: every __shfl executes with ALL 64 lanes active (shuffle-from-inactive-
// lane is undefined on CDNA — that was R9's bug); predication only on the use.
__global__ __launch_bounds__(256) void gather1_kernel(
        const int* __restrict__ srcS, const int* __restrict__ rowstart,
        const int* __restrict__ deg, const float* __restrict__ dinv,
        const _Float16* __restrict__ h1, const float* __restrict__ b1,
        float* __restrict__ h2, int n) {
    int t = threadIdx.x;
    int g = __builtin_amdgcn_readfirstlane(blockIdx.x * 4 + (t >> 6));
    int lane = t & 63;
    if (g >= n) return;
    int c = lane & 31;          // 4-col group
    int hsel = lane >> 5;       // 0 = lo half (edge A), 1 = hi half (edge B)

    float4 acc = make_float4(0.f, 0.f, 0.f, 0.f);
    if (hsel == 0) {            // self term (pre-scaled) on lo half only
        half4v v = ((const half4v*)(h1 + (size_t)g * 128))[c];
        acc.x = (float)v.x; acc.y = (float)v.y; acc.z = (float)v.z; acc.w = (float)v.w;
    }
    float dg = dinv[g];
    int beg = rowstart[g], end = beg + deg[g];
    int e = beg;
    while (e < end) {
        int rem = end - e;
        int sv = (lane < rem) ? srcS[e + lane] : 0;   // 64 edge indices per wave
        int chunk = rem < 64 ? rem : 64;
        int j = 0;
        for (; j + 16 <= chunk; j += 16) {            // 16 edges per iter, 8 loads
            int s0 = __shfl(sv, j + 0  + hsel), s1 = __shfl(sv, j + 2  + hsel);
            int s2 = __shfl(sv, j + 4  + hsel), s3 = __shfl(sv, j + 6  + hsel);
            int s4 = __shfl(sv, j + 8  + hsel), s5 = __shfl(sv, j + 10 + hsel);
            int s6 = __shfl(sv, j + 12 + hsel), s7 = __shfl(sv, j + 14 + hsel);
            half4v u0 = ((const half4v*)(h1 + (size_t)s0 * 128))[c];
            half4v u1 = ((const half4v*)(h1 + (size_t)s1 * 128))[c];
            half4v u2 = ((const half4v*)(h1 + (size_t)s2 * 128))[c];
            half4v u3 = ((const half4v*)(h1 + (size_t)s3 * 128))[c];
            half4v u4 = ((const half4v*)(h1 + (size_t)s4 * 128))[c];
            half4v u5 = ((const half4v*)(h1 + (size_t)s5 * 128))[c];
            half4v u6 = ((const half4v*)(h1 + (size_t)s6 * 128))[c];
            half4v u7 = ((const half4v*)(h1 + (size_t)s7 * 128))[c];
            acc.x += (float)u0.x; acc.y += (float)u0.y; acc.z += (float)u0.z; acc.w += (float)u0.w;
            acc.x += (float)u1.x; acc.y += (float)u1.y; acc.z += (float)u1.z; acc.w += (float)u1.w;
            acc.x += (float)u2.x; acc.y += (float)u2.y; acc.z += (float)u2.z; acc.w += (float)u2.w;
            acc.x += (float)u3.x; acc.y += (float)u3.y; acc.z += (float)u3.z; acc.w += (float)u3.w;
            acc.x += (float)u4.x; acc.y += (float)u4.y; acc.z += (float)u4.z; acc.w += (float)u4.w;
            acc.x += (float)u5.x; acc.y += (float)u5.y; acc.z += (float)u5.z; acc.w += (float)u5.w;
            acc.x += (float)u6.x; acc.y += (float)u6.y; acc.z += (float)u6.z; acc.w += (float)u6.w;
            acc.x += (float)u7.x; acc.y += (float)u7.y; acc.z += (float)u7.z; acc.w += (float)u7.w;
        }
        for (; j + 2 <= chunk; j += 2) {              // 2 edges per load (all lanes active)
            int s = __shfl(sv, j + hsel);
            half4v u = ((const half4v*)(h1 + (size_t)s * 128))[c];
            acc.x += (float)u.x; acc.y += (float)u.y; acc.z += (float)u.z; acc.w += (float)u.w;
        }
        if (j < chunk) {                              // odd tail
            int s = __shfl(sv, j);                    // ALL lanes shuffle (j uniform)
            if (hsel == 0) {                          // only lo half consumes
                half4v u = ((const half4v*)(h1 + (size_t)s * 128))[c];
                acc.x += (float)u.x; acc.y += (float)u.y; acc.z += (float)u.z; acc.w += (float)u.w;
            }
        }
        e += chunk;
    }
    // combine halves
    acc.x += __shfl_xor(acc.x, 32);
    acc.y += __shfl_xor(acc.y, 32);
    acc.z += __shfl_xor(acc.z, 32);
    acc.w += __shfl_xor(acc.w, 32);
    if (hsel == 0) {
        float4 b = ((const float4*)b1)[c];
        acc.x = fmaxf(dg * acc.x + b.x, 0.f);
        acc.y = fmaxf(dg * acc.y + b.y, 0.f);
        acc.z = fmaxf(dg * acc.z + b.z, 0.f);
        acc.w = fmaxf(dg * acc.w + b.w, 0.f);
        ((float4*)(h2 + (size_t)g * 128))[c] = acc;
    }
}

// ---------------- GEMM2: h3'[N,64] = fp16( dinv * (h2[N,128] @ W2[128,64]) ) ----------------
__global__ __launch_bounds__(256) void gemm_nk64(const float* __restrict__ x,
                                                 const float* __restrict__ W,
                                                 const float* __restrict__ dinv,
                                                 _Float16* __restrict__ h, int n) {
    __shared__ float xs[32][128];
    int t = threadIdx.x;
    int node0 = blockIdx.x * 32;
#pragma unroll
    for (int i = 0; i < 4; i++) {
        int fi = t + 256 * i;
        int row = fi >> 5, cv = fi & 31;
        float4 v = make_float4(0.f, 0.f, 0.f, 0.f);
        if (node0 + row < n) v = ((const float4*)x)[(size_t)(node0 + row) * 32 + cv];
        ((float4*)(&xs[0][0]))[fi] = v;
    }
    __syncthreads();

    int tx = t & 15, ty = t >> 4;
    int c0 = tx * 4;
    float acc[2][4];
#pragma unroll
    for (int i = 0; i < 2; i++)
#pragma unroll
        for (int j = 0; j < 4; j++) acc[i][j] = 0.f;

    for (int k = 0; k < 128; k++) {
        float4 w = *(const float4*)(W + k * 64 + c0);
#pragma unroll
        for (int i = 0; i < 2; i++) {
            float xval = xs[ty + 16 * i][k];
            acc[i][0] += xval * w.x;
            acc[i][1] += xval * w.y;
            acc[i][2] += xval * w.z;
            acc[i][3] += xval * w.w;
        }
    }
#pragma unroll
    for (int i = 0; i < 2; i++) {
        int node = node0 + ty + 16 * i;
        if (node < n) {
            float dv = dinv[node];
            half4v hv;
            hv.x = (_Float16)(acc[i][0] * dv);
            hv.y = (_Float16)(acc[i][1] * dv);
            hv.z = (_Float16)(acc[i][2] * dv);
            hv.w = (_Float16)(acc[i][3] * dv);
            *(half4v*)(h + (size_t)node * 64 + c0) = hv;
        }
    }
}

// ---------------- gather2: out = dg * agg(h3') + b2  (2 edges per VMEM instr) ----------------
__global__ __launch_bounds__(256) void gather2_kernel(
        const int* __restrict__ srcS, const int* __restrict__ rowstart,
        const int* __restrict__ deg, const float* __restrict__ dinv,
        const _Float16* __restrict__ h3, const float* __restrict__ b2,
        float* __restrict__ out, int n) {
    int t = threadIdx.x;
    int g = __builtin_amdgcn_readfirstlane(blockIdx.x * 4 + (t >> 6));
    int lane = t & 63;
    if (g >= n) return;
    int c = lane & 31;          // 2-col group
    int hsel = lane >> 5;

    float2 acc = make_float2(0.f, 0.f);
    if (hsel == 0) {            // self term (pre-scaled)
        half2v v = ((const half2v*)(h3 + (size_t)g * 64))[c];
        acc.x = (float)v.x; acc.y = (float)v.y;
    }
    float dg = dinv[g];
    int beg = rowstart[g], end = beg + deg[g];
    int e = beg;
    while (e < end) {
        int rem = end - e;
        int sv = (lane < rem) ? srcS[e + lane] : 0;
        int chunk = rem < 64 ? rem : 64;
        int j = 0;
        for (; j + 16 <= chunk; j += 16) {
            int s0 = __shfl(sv, j + 0  + hsel), s1 = __shfl(sv, j + 2  + hsel);
            int s2 = __shfl(sv, j + 4  + hsel), s3 = __shfl(sv, j + 6  + hsel);
            int s4 = __shfl(sv, j + 8  + hsel), s5 = __shfl(sv, j + 10 + hsel);
            int s6 = __shfl(sv, j + 12 + hsel), s7 = __shfl(sv, j + 14 + hsel);
            half2v u0 = ((const half2v*)(h3 + (size_t)s0 * 64))[c];
            half2v u1 = ((const half2v*)(h3 + (size_t)s1 * 64))[c];
            half2v u2 = ((const half2v*)(h3 + (size_t)s2 * 64))[c];
            half2v u3 = ((const half2v*)(h3 + (size_t)s3 * 64))[c];
            half2v u4 = ((const half2v*)(h3 + (size_t)s4 * 64))[c];
            half2v u5 = ((const half2v*)(h3 + (size_t)s5 * 64))[c];
            half2v u6 = ((const half2v*)(h3 + (size_t)s6 * 64))[c];
            half2v u7 = ((const half2v*)(h3 + (size_t)s7 * 64))[c];
            acc.x += (float)u0.x; acc.y += (float)u0.y;
            acc.x += (float)u1.x; acc.y += (float)u1.y;
            acc.x += (float)u2.x; acc.y += (float)u2.y;
            acc.x += (float)u3.x; acc.y += (float)u3.y;
            acc.x += (float)u4.x; acc.y += (float)u4.y;
            acc.x += (float)u5.x; acc.y += (float)u5.y;
            acc.x += (float)u6.x; acc.y += (float)u6.y;
            acc.x += (float)u7.x; acc.y += (float)u7.y;
        }
        for (; j + 2 <= chunk; j += 2) {
            int s = __shfl(sv, j + hsel);
            half2v u = ((const half2v*)(h3 + (size_t)s * 64))[c];
            acc.x += (float)u.x; acc.y += (float)u.y;
        }
        if (j < chunk) {                              // odd tail
            int s = __shfl(sv, j);                    // ALL lanes shuffle
            if (hsel == 0) {
                half2v u = ((const half2v*)(h3 + (size_t)s * 64))[c];
                acc.x += (float)u.x; acc.y += (float)u.y;
            }
        }
        e += chunk;
    }
    acc.x += __shfl_xor(acc.x, 32);
    acc.y += __shfl_xor(acc.y, 32);
    if (hsel == 0) {
        float2 b = ((const float2*)b2)[c];
        ((float2*)(out + (size_t)g * 64))[c] =
            make_float2(dg * acc.x + b.x, dg * acc.y + b.y);
    }
}

extern "C" void kernel_launch(void* const* d_in, const int* in_sizes, int n_in,
                              void* d_out, int out_size, void* d_ws, size_t ws_size,
                              hipStream_t stream) {
    const float* x  = (const float*)d_in[0];
    const int*   ei = (const int*)d_in[1];
    const float* W1 = (const float*)d_in[2];
    const float* b1 = (const float*)d_in[3];
    const float* W2 = (const float*)d_in[4];
    const float* b2 = (const float*)d_in[5];
    float* out = (float*)d_out;

    const int n = in_sizes[0] / 128;   // 100000
    const int E = in_sizes[1] / 2;     // 1600000
    const int* src = ei;
    const int* dst = ei + E;
    const int nbkt = (n + 511) >> 9;   // 196 coarse buckets (512 nodes each)

    char* ws = (char*)d_ws;
    size_t off = 0;
    auto carve = [&](size_t bytes) -> char* {
        char* p = ws + off;
        off += (bytes + 255) & ~(size_t)255;
        return p;
    };
    // bktCnt/ovfCnt contiguous -> single small memset
    int*   bktCnt    = (int*)carve((size_t)NBKT_MAX * 4);
    int*   ovfCnt    = (int*)carve(4);
    size_t msz       = (size_t)((char*)ovfCnt - (char*)bktCnt) + 256;
    int*   deg       = (int*)carve((size_t)n * 4);       // fully written by deg_scan
    float* dinv      = (float*)carve((size_t)n * 4);
    int*   rowstart  = (int*)carve((size_t)n * 4);
    int*   blockSums = (int*)carve((size_t)NBKT_MAX * 4);
    int*   srcSorted = (int*)carve((size_t)E * 4);
    _Float16* Wt     = (_Float16*)carve((size_t)128 * 128 * 2);    // W1^T fp16
    int2*  ovfBuf    = (int2*)carve((size_t)OVF_CAP * 8);
    _Float16* h1     = (_Float16*)carve((size_t)n * 128 * 2);      // x@W1 fp16 (scaled in-place); then h3
    float* bufB      = (float*)carve((size_t)n * 128 * 4);         // pairPart (pass1-2), then h2
    unsigned* pairPart = (unsigned*)bufB;  // 12.8MB <= 51.2MB, dead before gather1 writes h2
    _Float16* h3     = h1;                 // gemm_nk64 writes after gather1 finishes reading h1

    hipMemsetAsync(bktCnt, 0, msz, stream);

    wcast_kernel<<<64, 256, 0, stream>>>(W1, Wt);

    // fused partition | gemm1 (4 GEMM : 1 sort per 5-group)
    int sortBlocks = (E + 4095) / 4096;             // 391
    int gemmBlocks = (n + 63) / 64;                 // 1563
    int gGroups = (gemmBlocks + 3) / 4;             // 391
    int groups = (sortBlocks > gGroups) ? sortBlocks : gGroups;
    int G = groups * 5;
    part_gemm1_kernel<<<G, 256, 0, stream>>>(src, dst, bktCnt, ovfCnt, ovfBuf,
                                             pairPart, E, x, Wt, h1, n, nbkt);

    // deg + dinv + bucket-local rowstart (fused histogram + 512-wide scan)
    deg_scan_kernel<<<nbkt, 512, 0, stream>>>(pairPart, bktCnt, ovfCnt, ovfBuf,
                                              deg, dinv, rowstart, blockSums, n);
    scan2_kernel<<<1, 512, 0, stream>>>(blockSums, nbkt);
    // rowstart += bucket base; h1 *= dinv (fused)
    scan3_scale_kernel<<<(n * 16 + 255) / 256, 256, 0, stream>>>(rowstart, blockSums, h1, dinv, n);

    // exact scatter within buckets
    scatter2_kernel<<<nbkt, 256, 0, stream>>>(pairPart, bktCnt, ovfCnt, ovfBuf,
                                              rowstart, srcSorted, n);

    // layer 1 aggregation: h2 = relu(dg * agg(h1') + b1)
    gather1_kernel<<<(n + 3) / 4, 256, 0, stream>>>(srcSorted, rowstart, deg, dinv,
                                                    h1, b1, bufB, n);

    // layer 2: h3' = fp16(dinv * (h2@W2)) (reuses h1 buffer) ; out = dg * agg(h3') + b2
    gemm_nk64<<<(n + 31) / 32, 256, 0, stream>>>(bufB, W2, dinv, h3, n);
    gather2_kernel<<<(n + 3) / 4, 256, 0, stream>>>(srcSorted, rowstart, deg, dinv,
                                                    h3, b2, out, n);
}

// Round 12
// 335.071 us; speedup vs baseline: 1.2272x; 1.0295x over previous
//
#include <hip/hip_runtime.h>

typedef _Float16 half2v __attribute__((ext_vector_type(2)));
typedef _Float16 half4v __attribute__((ext_vector_type(4)));
typedef _Float16 f16x8 __attribute__((ext_vector_type(8)));
typedef float f32x4 __attribute__((ext_vector_type(4)));

#define NBKT_MAX 256     // n<=131072 with 512-node buckets
#define BKT_CAP  16384   // per-bucket pair capacity (mean 8163, sigma~90 -> +91 sigma)
#define OVF_CAP  8192    // overflow list capacity (expected use: 0)
#define SRC_MASK 0x1FFFF // 17-bit src (n < 131072)

// ---------------- W1 cast + transpose: Wt[col][k] fp16 ----------------
__global__ void wcast_kernel(const float* __restrict__ W, _Float16* __restrict__ Wt) {
    int t = blockIdx.x * 256 + threadIdx.x;
    if (t < 128 * 128) {
        int k = t >> 7, c = t & 127;
        Wt[c * 128 + k] = (_Float16)W[k * 128 + c];
    }
}

// ---------------- fused: partition (4096-edge 2-pass, int4-batched, packed 4B) | GEMM1 ----------------
__global__ __launch_bounds__(256) void part_gemm1_kernel(
        const int* __restrict__ src, const int* __restrict__ dst,
        int* __restrict__ bktCnt, int* __restrict__ ovfCnt,
        int2* __restrict__ ovfBuf, unsigned* __restrict__ pairPart, int E,
        const float* __restrict__ x, const _Float16* __restrict__ Wt,
        _Float16* __restrict__ h, int n, int nbkt) {
    __shared__ union {
        _Float16 xs_h[64][128];   // 16 KB
        struct { int cnt[NBKT_MAX]; int gbase[NBKT_MAX]; int off[NBKT_MAX]; } s;
    } u;
    int bid = blockIdx.x;
    int t = threadIdx.x;
    if (bid % 5 != 4) {
        // ---- GEMM1: 64 nodes x 128 cols, mfma_f32_16x16x32_f16 ----
        int gb = (bid / 5) * 4 + (bid % 5);
        int node0 = gb * 64;
        if (node0 >= n) return;

        // stage x tile -> fp16 LDS, swizzled: byte_in_row = seg*16 ^ ((row&7)<<4)
#pragma unroll
        for (int i = 0; i < 4; i++) {
            int fi = t + 256 * i;           // 1024 slots of 8 halves
            int row = fi >> 4, seg = fi & 15;
            float4 a = make_float4(0.f, 0.f, 0.f, 0.f);
            float4 b4 = make_float4(0.f, 0.f, 0.f, 0.f);
            if (node0 + row < n) {
                const float4* xr = (const float4*)(x + (size_t)(node0 + row) * 128 + seg * 8);
                a = xr[0]; b4 = xr[1];
            }
            f16x8 hv;
            hv[0] = (_Float16)a.x;  hv[1] = (_Float16)a.y;
            hv[2] = (_Float16)a.z;  hv[3] = (_Float16)a.w;
            hv[4] = (_Float16)b4.x; hv[5] = (_Float16)b4.y;
            hv[6] = (_Float16)b4.z; hv[7] = (_Float16)b4.w;
            int byte = row * 256 + ((seg * 16) ^ ((row & 7) << 4));
            *(f16x8*)((char*)&u.xs_h[0][0] + byte) = hv;
        }
        __syncthreads();

        int wid = t >> 6, l = t & 63;
        int row0 = wid * 16;                 // wave's 16-row slice
        int arow = row0 + (l & 15);
        int kgrp = l >> 4;                   // 0..3
        f32x4 acc[8];
#pragma unroll
        for (int ct = 0; ct < 8; ct++) acc[ct] = (f32x4){0.f, 0.f, 0.f, 0.f};

        const char* xbase = (const char*)&u.xs_h[0][0] + arow * 256;
#pragma unroll
        for (int ks = 0; ks < 4; ks++) {
            int abyte = ((ks * 64 + kgrp * 16) ^ ((arow & 7) << 4));
            f16x8 afrag = *(const f16x8*)(xbase + abyte);
#pragma unroll
            for (int ct = 0; ct < 8; ct++) {
                f16x8 bfrag = *(const f16x8*)(Wt + (ct * 16 + (l & 15)) * 128 + ks * 32 + kgrp * 8);
                acc[ct] = __builtin_amdgcn_mfma_f32_16x16x32_f16(afrag, bfrag, acc[ct], 0, 0, 0);
            }
        }

        // epilogue: C/D row = (l>>4)*4 + reg, col = ct*16 + (l&15); raw fp16
        int r0 = row0 + kgrp * 4;
#pragma unroll
        for (int ct = 0; ct < 8; ct++) {
            int col = ct * 16 + (l & 15);
#pragma unroll
            for (int r = 0; r < 4; r++) {
                int node = node0 + r0 + r;
                if (node < n)
                    h[(size_t)node * 128 + col] = (_Float16)acc[ct][r];
            }
        }
    } else {
        // ---- partition: one 4096-edge tile per block, 8-edge int4 batches ----
        int sb = bid / 5;
        int base = sb * 4096;
        if (base >= E) return;
        int eend = base + 4096; if (eend > E) eend = E;
        for (int i = t; i < nbkt; i += 256) u.s.cnt[i] = 0;
        __syncthreads();
        // phase A: histogram (8 dst per thread per sweep, 2 int4 loads)
        for (int e0 = base + t * 8; e0 < eend; e0 += 2048) {
            if (e0 + 8 <= eend) {
                int4 d0 = *(const int4*)(dst + e0);
                int4 d1 = *(const int4*)(dst + e0 + 4);
                atomicAdd(&u.s.cnt[d0.x >> 9], 1); atomicAdd(&u.s.cnt[d0.y >> 9], 1);
                atomicAdd(&u.s.cnt[d0.z >> 9], 1); atomicAdd(&u.s.cnt[d0.w >> 9], 1);
                atomicAdd(&u.s.cnt[d1.x >> 9], 1); atomicAdd(&u.s.cnt[d1.y >> 9], 1);
                atomicAdd(&u.s.cnt[d1.z >> 9], 1); atomicAdd(&u.s.cnt[d1.w >> 9], 1);
            } else {
                for (int e = e0; e < eend; e++) atomicAdd(&u.s.cnt[dst[e] >> 9], 1);
            }
        }
        __syncthreads();
        // phase B: claim contiguous chunks
        for (int i = t; i < nbkt; i += 256) {
            u.s.off[i] = 0;
            int c = u.s.cnt[i];
            if (c > 0) u.s.gbase[i] = atomicAdd(&bktCnt[i], c);
        }
        __syncthreads();
        // phase C: packed scatter (8 edges per thread per sweep)
        for (int e0 = base + t * 8; e0 < eend; e0 += 2048) {
            if (e0 + 8 <= eend) {
                int4 s0 = *(const int4*)(src + e0);
                int4 s1 = *(const int4*)(src + e0 + 4);
                int4 d0 = *(const int4*)(dst + e0);
                int4 d1 = *(const int4*)(dst + e0 + 4);
                int ss[8] = {s0.x, s0.y, s0.z, s0.w, s1.x, s1.y, s1.z, s1.w};
                int dd[8] = {d0.x, d0.y, d0.z, d0.w, d1.x, d1.y, d1.z, d1.w};
#pragma unroll
                for (int j = 0; j < 8; j++) {
                    int b = dd[j] >> 9;
                    int slot = u.s.gbase[b] + atomicAdd(&u.s.off[b], 1);
                    unsigned p = ((unsigned)(dd[j] & 511) << 17) | (unsigned)ss[j];
                    if (slot < BKT_CAP) {
                        pairPart[(size_t)b * BKT_CAP + slot] = p;
                    } else {
                        int op = atomicAdd(ovfCnt, 1);
                        if (op < OVF_CAP) ovfBuf[op] = make_int2((int)p, b);
                    }
                }
            } else {
                for (int e = e0; e < eend; e++) {
                    int s = src[e], d = dst[e];
                    int b = d >> 9;
                    int slot = u.s.gbase[b] + atomicAdd(&u.s.off[b], 1);
                    unsigned p = ((unsigned)(d & 511) << 17) | (unsigned)s;
                    if (slot < BKT_CAP) {
                        pairPart[(size_t)b * BKT_CAP + slot] = p;
                    } else {
                        int op = atomicAdd(ovfCnt, 1);
                        if (op < OVF_CAP) ovfBuf[op] = make_int2((int)p, b);
                    }
                }
            }
        }
    }
}

// ---------------- bucket_process: base-scan + histogram + scan + deg/dinv/rowstart
//                  + srcSorted scatter + h1 scale — one kernel, one block per bucket ----------------
__global__ __launch_bounds__(512) void bucket_process_kernel(
        const unsigned* __restrict__ pairPart, const int* __restrict__ bktCnt,
        const int* __restrict__ ovfCnt, const int2* __restrict__ ovfBuf,
        int* __restrict__ deg, float* __restrict__ dinv, int* __restrict__ rowstart,
        int* __restrict__ srcSorted, _Float16* __restrict__ h1, int n, int nbkt) {
    __shared__ int hist[512];
    __shared__ float sdinv[512];
    int b = blockIdx.x;
    int t = threadIdx.x;

    // phase 0: bucket base = exclusive prefix of bktCnt (in-LDS 256-scan, redundant per block)
    if (t < 256) hist[t] = (t < nbkt) ? bktCnt[t] : 0;
    __syncthreads();
    for (int off = 1; off < 256; off <<= 1) {
        int add = (t < 256 && t >= off) ? hist[t - off] : 0;
        __syncthreads();
        if (t < 256) hist[t] += add;
        __syncthreads();
    }
    int myBase = hist[b] - bktCnt[b];   // exclusive
    __syncthreads();

    // phase 1: histogram bucket pairs into hist[512]
    hist[t] = 0;
    __syncthreads();
    int cnt = bktCnt[b];
    if (cnt > BKT_CAP) cnt = BKT_CAP;
    const unsigned* bp = pairPart + (size_t)b * BKT_CAP;
    for (int e0 = t * 4; e0 < cnt; e0 += 2048) {
        if (e0 + 4 <= cnt) {
            uint4 p = *(const uint4*)(bp + e0);
            atomicAdd(&hist[p.x >> 17], 1); atomicAdd(&hist[p.y >> 17], 1);
            atomicAdd(&hist[p.z >> 17], 1); atomicAdd(&hist[p.w >> 17], 1);
        } else {
            for (int e = e0; e < cnt; e++) atomicAdd(&hist[bp[e] >> 17], 1);
        }
    }
    int oc = *ovfCnt;
    if (oc > 0) {
        if (oc > OVF_CAP) oc = OVF_CAP;
        for (int i = t; i < oc; i += 512) {
            int2 p = ovfBuf[i];
            if (p.y == b) atomicAdd(&hist[((unsigned)p.x) >> 17], 1);
        }
    }
    __syncthreads();

    // phase 2: 512-wide inclusive scan -> deg/dinv/rowstart + cursors
    int v = hist[t];
#pragma unroll
    for (int off = 1; off < 512; off <<= 1) {
        int add = (t >= off) ? hist[t - off] : 0;
        __syncthreads();
        hist[t] += add;
        __syncthreads();
    }
    int cur = myBase + hist[t] - v;     // global rowstart for this node
    float dv = rsqrtf((float)(v + 1));  // +1 = self loop
    int node = (b << 9) + t;
    if (node < n) {
        deg[node] = v;
        dinv[node] = dv;
        rowstart[node] = cur;
    }
    sdinv[t] = dv;
    hist[t] = cur;                      // own slot only; becomes scatter cursor
    __syncthreads();

    // phase 3: scatter srcSorted (4-batched)
    for (int e0 = t * 4; e0 < cnt; e0 += 2048) {
        if (e0 + 4 <= cnt) {
            uint4 p = *(const uint4*)(bp + e0);
            int p0 = atomicAdd(&hist[p.x >> 17], 1);
            int p1 = atomicAdd(&hist[p.y >> 17], 1);
            int p2 = atomicAdd(&hist[p.z >> 17], 1);
            int p3 = atomicAdd(&hist[p.w >> 17], 1);
            srcSorted[p0] = (int)(p.x & SRC_MASK);
            srcSorted[p1] = (int)(p.y & SRC_MASK);
            srcSorted[p2] = (int)(p.z & SRC_MASK);
            srcSorted[p3] = (int)(p.w & SRC_MASK);
        } else {
            for (int e = e0; e < cnt; e++) {
                unsigned p = bp[e];
                int pos = atomicAdd(&hist[p >> 17], 1);
                srcSorted[pos] = (int)(p & SRC_MASK);
            }
        }
    }
    if (oc > 0) {
        for (int i = t; i < oc; i += 512) {
            int2 p = ovfBuf[i];
            if (p.y == b) {
                int pos = atomicAdd(&hist[((unsigned)p.x) >> 17], 1);
                srcSorted[pos] = (int)((unsigned)p.x & SRC_MASK);
            }
        }
    }

    // phase 4: scale this bucket's h1 rows by dinv (coalesced, overlaps other blocks' stalls)
    int node0 = b << 9;
    int rows = n - node0; if (rows > 512) rows = 512;
    if (rows > 0) {
        int total = rows * 16;              // f16x8 slots
        f16x8* hrow = (f16x8*)(h1 + (size_t)node0 * 128);
        for (int i = t; i < total; i += 512) {
            float dvv = sdinv[i >> 4];
            f16x8 vv = hrow[i];
#pragma unroll
            for (int k = 0; k < 8; k++) vv[k] = (_Float16)((float)vv[k] * dvv);
            hrow[i] = vv;
        }
    }
}

// ---------------- gather1: h2 = relu(dg * agg(h1') + b1)  [proven R8 shape] ----------------
__global__ __launch_bounds__(256) void gather1_kernel(
        const int* __restrict__ srcS, const int* __restrict__ rowstart,
        const int* __restrict__ deg, const float* __restrict__ dinv,
        const _Float16* __restrict__ h1, const float* __restrict__ b1,
        float* __restrict__ h2, int n) {
    int t = threadIdx.x;
    int g = __builtin_amdgcn_readfirstlane(blockIdx.x * 4 + (t >> 6));
    int lane = t & 63;
    if (g >= n) return;

    float dg = dinv[g];
    half2v sv0 = ((const half2v*)(h1 + (size_t)g * 128))[lane];  // self term (pre-scaled)
    float2 acc = make_float2((float)sv0.x, (float)sv0.y);
    int beg = rowstart[g], end = beg + deg[g];
    int e = beg;
    while (e < end) {
        int rem = end - e;
        int sv = (lane < rem) ? srcS[e + lane] : 0;   // 1 coalesced load / 64 edges
        int chunk = rem < 64 ? rem : 64;
        int j = 0;
        for (; j + 8 <= chunk; j += 8) {
            int s0 = __shfl(sv, j + 0), s1 = __shfl(sv, j + 1);
            int s2 = __shfl(sv, j + 2), s3 = __shfl(sv, j + 3);
            int s4 = __shfl(sv, j + 4), s5 = __shfl(sv, j + 5);
            int s6 = __shfl(sv, j + 6), s7 = __shfl(sv, j + 7);
            half2v u0 = ((const half2v*)(h1 + (size_t)s0 * 128))[lane];
            half2v u1 = ((const half2v*)(h1 + (size_t)s1 * 128))[lane];
            half2v u2 = ((const half2v*)(h1 + (size_t)s2 * 128))[lane];
            half2v u3 = ((const half2v*)(h1 + (size_t)s3 * 128))[lane];
            half2v u4 = ((const half2v*)(h1 + (size_t)s4 * 128))[lane];
            half2v u5 = ((const half2v*)(h1 + (size_t)s5 * 128))[lane];
            half2v u6 = ((const half2v*)(h1 + (size_t)s6 * 128))[lane];
            half2v u7 = ((const half2v*)(h1 + (size_t)s7 * 128))[lane];
            acc.x += (float)u0.x; acc.y += (float)u0.y;
            acc.x += (float)u1.x; acc.y += (float)u1.y;
            acc.x += (float)u2.x; acc.y += (float)u2.y;
            acc.x += (float)u3.x; acc.y += (float)u3.y;
            acc.x += (float)u4.x; acc.y += (float)u4.y;
            acc.x += (float)u5.x; acc.y += (float)u5.y;
            acc.x += (float)u6.x; acc.y += (float)u6.y;
            acc.x += (float)u7.x; acc.y += (float)u7.y;
        }
        for (; j < chunk; j++) {
            int s = __shfl(sv, j);
            half2v u = ((const half2v*)(h1 + (size_t)s * 128))[lane];
            acc.x += (float)u.x; acc.y += (float)u.y;
        }
        e += chunk;
    }
    float2 b = ((const float2*)b1)[lane];
    acc.x = fmaxf(dg * acc.x + b.x, 0.f);
    acc.y = fmaxf(dg * acc.y + b.y, 0.f);
    ((float2*)(h2 + (size_t)g * 128))[lane] = acc;
}

// ---------------- GEMM2: h3'[N,64] = fp16( dinv * (h2[N,128] @ W2[128,64]) ) ----------------
__global__ __launch_bounds__(256) void gemm_nk64(const float* __restrict__ x,
                                                 const float* __restrict__ W,
                                                 const float* __restrict__ dinv,
                                                 _Float16* __restrict__ h, int n) {
    __shared__ float xs[32][128];
    int t = threadIdx.x;
    int node0 = blockIdx.x * 32;
#pragma unroll
    for (int i = 0; i < 4; i++) {
        int fi = t + 256 * i;
        int row = fi >> 5, cv = fi & 31;
        float4 v = make_float4(0.f, 0.f, 0.f, 0.f);
        if (node0 + row < n) v = ((const float4*)x)[(size_t)(node0 + row) * 32 + cv];
        ((float4*)(&xs[0][0]))[fi] = v;
    }
    __syncthreads();

    int tx = t & 15, ty = t >> 4;
    int c0 = tx * 4;
    float acc[2][4];
#pragma unroll
    for (int i = 0; i < 2; i++)
#pragma unroll
        for (int j = 0; j < 4; j++) acc[i][j] = 0.f;

    for (int k = 0; k < 128; k++) {
        float4 w = *(const float4*)(W + k * 64 + c0);
#pragma unroll
        for (int i = 0; i < 2; i++) {
            float xval = xs[ty + 16 * i][k];
            acc[i][0] += xval * w.x;
            acc[i][1] += xval * w.y;
            acc[i][2] += xval * w.z;
            acc[i][3] += xval * w.w;
        }
    }
#pragma unroll
    for (int i = 0; i < 2; i++) {
        int node = node0 + ty + 16 * i;
        if (node < n) {
            float dv = dinv[node];
            half4v hv;
            hv.x = (_Float16)(acc[i][0] * dv);
            hv.y = (_Float16)(acc[i][1] * dv);
            hv.z = (_Float16)(acc[i][2] * dv);
            hv.w = (_Float16)(acc[i][3] * dv);
            *(half4v*)(h + (size_t)node * 64 + c0) = hv;
        }
    }
}

// ---------------- gather2: out = dg * agg(h3') + b2  [proven R8 shape] ----------------
__global__ __launch_bounds__(256) void gather2_kernel(
        const int* __restrict__ srcS, const int* __restrict__ rowstart,
        const int* __restrict__ deg, const float* __restrict__ dinv,
        const _Float16* __restrict__ h3, const float* __restrict__ b2,
        float* __restrict__ out, int n) {
    int t = threadIdx.x;
    int g = __builtin_amdgcn_readfirstlane(blockIdx.x * 4 + (t >> 6));
    int lane = t & 63;
    if (g >= n) return;
    float dg = dinv[g];
    float acc = (float)h3[(size_t)g * 64 + lane];   // self term (pre-scaled)
    int beg = rowstart[g], end = beg + deg[g];
    int e = beg;
    while (e < end) {
        int rem = end - e;
        int sv = (lane < rem) ? srcS[e + lane] : 0;
        int chunk = rem < 64 ? rem : 64;
        int j = 0;
        for (; j + 8 <= chunk; j += 8) {
            int s0 = __shfl(sv, j + 0), s1 = __shfl(sv, j + 1);
            int s2 = __shfl(sv, j + 2), s3 = __shfl(sv, j + 3);
            int s4 = __shfl(sv, j + 4), s5 = __shfl(sv, j + 5);
            int s6 = __shfl(sv, j + 6), s7 = __shfl(sv, j + 7);
            float u0 = (float)h3[(size_t)s0 * 64 + lane];
            float u1 = (float)h3[(size_t)s1 * 64 + lane];
            float u2 = (float)h3[(size_t)s2 * 64 + lane];
            float u3 = (float)h3[(size_t)s3 * 64 + lane];
            float u4 = (float)h3[(size_t)s4 * 64 + lane];
            float u5 = (float)h3[(size_t)s5 * 64 + lane];
            float u6 = (float)h3[(size_t)s6 * 64 + lane];
            float u7 = (float)h3[(size_t)s7 * 64 + lane];
            acc += u0 + u1 + u2 + u3 + u4 + u5 + u6 + u7;
        }
        for (; j < chunk; j++) {
            int s = __shfl(sv, j);
            acc += (float)h3[(size_t)s * 64 + lane];
        }
        e += chunk;
    }
    out[(size_t)g * 64 + lane] = dg * acc + b2[lane];
}

extern "C" void kernel_launch(void* const* d_in, const int* in_sizes, int n_in,
                              void* d_out, int out_size, void* d_ws, size_t ws_size,
                              hipStream_t stream) {
    const float* x  = (const float*)d_in[0];
    const int*   ei = (const int*)d_in[1];
    const float* W1 = (const float*)d_in[2];
    const float* b1 = (const float*)d_in[3];
    const float* W2 = (const float*)d_in[4];
    const float* b2 = (const float*)d_in[5];
    float* out = (float*)d_out;

    const int n = in_sizes[0] / 128;   // 100000
    const int E = in_sizes[1] / 2;     // 1600000
    const int* src = ei;
    const int* dst = ei + E;
    const int nbkt = (n + 511) >> 9;   // 196 coarse buckets (512 nodes each)

    char* ws = (char*)d_ws;
    size_t off = 0;
    auto carve = [&](size_t bytes) -> char* {
        char* p = ws + off;
        off += (bytes + 255) & ~(size_t)255;
        return p;
    };
    // bktCnt/ovfCnt contiguous -> single small memset
    int*   bktCnt    = (int*)carve((size_t)NBKT_MAX * 4);
    int*   ovfCnt    = (int*)carve(4);
    size_t msz       = (size_t)((char*)ovfCnt - (char*)bktCnt) + 256;
    int*   deg       = (int*)carve((size_t)n * 4);       // written by bucket_process
    float* dinv      = (float*)carve((size_t)n * 4);
    int*   rowstart  = (int*)carve((size_t)n * 4);
    int*   srcSorted = (int*)carve((size_t)E * 4);
    _Float16* Wt     = (_Float16*)carve((size_t)128 * 128 * 2);    // W1^T fp16
    int2*  ovfBuf    = (int2*)carve((size_t)OVF_CAP * 8);
    _Float16* h1     = (_Float16*)carve((size_t)n * 128 * 2);      // x@W1 fp16 (scaled in-place); then h3
    float* bufB      = (float*)carve((size_t)n * 128 * 4);         // pairPart (pass1-2), then h2
    unsigned* pairPart = (unsigned*)bufB;  // 12.8MB <= 51.2MB, dead before gather1 writes h2
    _Float16* h3     = h1;                 // gemm_nk64 writes after gather1 finishes reading h1

    hipMemsetAsync(bktCnt, 0, msz, stream);

    wcast_kernel<<<64, 256, 0, stream>>>(W1, Wt);

    // fused partition | gemm1 (4 GEMM : 1 sort per 5-group)
    int sortBlocks = (E + 4095) / 4096;             // 391
    int gemmBlocks = (n + 63) / 64;                 // 1563
    int gGroups = (gemmBlocks + 3) / 4;             // 391
    int groups = (sortBlocks > gGroups) ? sortBlocks : gGroups;
    int G = groups * 5;
    part_gemm1_kernel<<<G, 256, 0, stream>>>(src, dst, bktCnt, ovfCnt, ovfBuf,
                                             pairPart, E, x, Wt, h1, n, nbkt);

    // one kernel: base-scan + histogram + scan + deg/dinv/rowstart + scatter + h1 scale
    bucket_process_kernel<<<nbkt, 512, 0, stream>>>(pairPart, bktCnt, ovfCnt, ovfBuf,
                                                    deg, dinv, rowstart, srcSorted,
                                                    h1, n, nbkt);

    // layer 1 aggregation: h2 = relu(dg * agg(h1') + b1)
    gather1_kernel<<<(n + 3) / 4, 256, 0, stream>>>(srcSorted, rowstart, deg, dinv,
                                                    h1, b1, bufB, n);

    // layer 2: h3' = fp16(dinv * (h2@W2)) (reuses h1 buffer) ; out = dg * agg(h3') + b2
    gemm_nk64<<<(n + 31) / 32, 256, 0, stream>>>(bufB, W2, dinv, h3, n);
    gather2_kernel<<<(n + 3) / 4, 256, 0, stream>>>(srcSorted, rowstart, deg, dinv,
                                                    h3, b2, out, n);
}

// Round 15
// 333.957 us; speedup vs baseline: 1.2313x; 1.0033x over previous
//
#include <hip/hip_runtime.h>

typedef _Float16 half2v __attribute__((ext_vector_type(2)));
typedef _Float16 half4v __attribute__((ext_vector_type(4)));
typedef _Float16 f16x8 __attribute__((ext_vector_type(8)));
typedef float f32x4 __attribute__((ext_vector_type(4)));

#define NBKT_MAX 256     // n<=131072 with 512-node buckets
#define BKT_CAP  16384   // per-bucket pair capacity (mean 8163, sigma~90 -> +91 sigma)
#define OVF_CAP  8192    // overflow list capacity (expected use: 0)
#define SRC_MASK 0x1FFFF // 17-bit src (n < 131072)

// ---------------- W1 cast + transpose: Wt[col][k] fp16 ----------------
__global__ void wcast_kernel(const float* __restrict__ W, _Float16* __restrict__ Wt) {
    int t = blockIdx.x * 256 + threadIdx.x;
    if (t < 128 * 128) {
        int k = t >> 7, c = t & 127;
        Wt[c * 128 + k] = (_Float16)W[k * 128 + c];
    }
}

// ---------------- fused: partition (4096-edge 2-pass, int4-batched, packed 4B) | GEMM1 ----------------
__global__ __launch_bounds__(256) void part_gemm1_kernel(
        const int* __restrict__ src, const int* __restrict__ dst,
        int* __restrict__ bktCnt, int* __restrict__ ovfCnt,
        int2* __restrict__ ovfBuf, unsigned* __restrict__ pairPart, int E,
        const float* __restrict__ x, const _Float16* __restrict__ Wt,
        _Float16* __restrict__ h, int n, int nbkt) {
    __shared__ union {
        _Float16 xs_h[64][128];   // 16 KB
        struct { int cnt[NBKT_MAX]; int gbase[NBKT_MAX]; int off[NBKT_MAX]; } s;
    } u;
    int bid = blockIdx.x;
    int t = threadIdx.x;
    if (bid % 5 != 4) {
        // ---- GEMM1: 64 nodes x 128 cols, mfma_f32_16x16x32_f16 ----
        int gb = (bid / 5) * 4 + (bid % 5);
        int node0 = gb * 64;
        if (node0 >= n) return;

        // stage x tile -> fp16 LDS, swizzled: byte_in_row = seg*16 ^ ((row&7)<<4)
#pragma unroll
        for (int i = 0; i < 4; i++) {
            int fi = t + 256 * i;           // 1024 slots of 8 halves
            int row = fi >> 4, seg = fi & 15;
            float4 a = make_float4(0.f, 0.f, 0.f, 0.f);
            float4 b4 = make_float4(0.f, 0.f, 0.f, 0.f);
            if (node0 + row < n) {
                const float4* xr = (const float4*)(x + (size_t)(node0 + row) * 128 + seg * 8);
                a = xr[0]; b4 = xr[1];
            }
            f16x8 hv;
            hv[0] = (_Float16)a.x;  hv[1] = (_Float16)a.y;
            hv[2] = (_Float16)a.z;  hv[3] = (_Float16)a.w;
            hv[4] = (_Float16)b4.x; hv[5] = (_Float16)b4.y;
            hv[6] = (_Float16)b4.z; hv[7] = (_Float16)b4.w;
            int byte = row * 256 + ((seg * 16) ^ ((row & 7) << 4));
            *(f16x8*)((char*)&u.xs_h[0][0] + byte) = hv;
        }
        __syncthreads();

        int wid = t >> 6, l = t & 63;
        int row0 = wid * 16;                 // wave's 16-row slice
        int arow = row0 + (l & 15);
        int kgrp = l >> 4;                   // 0..3
        f32x4 acc[8];
#pragma unroll
        for (int ct = 0; ct < 8; ct++) acc[ct] = (f32x4){0.f, 0.f, 0.f, 0.f};

        const char* xbase = (const char*)&u.xs_h[0][0] + arow * 256;
#pragma unroll
        for (int ks = 0; ks < 4; ks++) {
            int abyte = ((ks * 64 + kgrp * 16) ^ ((arow & 7) << 4));
            f16x8 afrag = *(const f16x8*)(xbase + abyte);
#pragma unroll
            for (int ct = 0; ct < 8; ct++) {
                f16x8 bfrag = *(const f16x8*)(Wt + (ct * 16 + (l & 15)) * 128 + ks * 32 + kgrp * 8);
                acc[ct] = __builtin_amdgcn_mfma_f32_16x16x32_f16(afrag, bfrag, acc[ct], 0, 0, 0);
            }
        }

        // epilogue: C/D row = (l>>4)*4 + reg, col = ct*16 + (l&15); raw fp16 (R11 proven)
        int r0 = row0 + kgrp * 4;
#pragma unroll
        for (int ct = 0; ct < 8; ct++) {
            int col = ct * 16 + (l & 15);
#pragma unroll
            for (int r = 0; r < 4; r++) {
                int node = node0 + r0 + r;
                if (node < n)
                    h[(size_t)node * 128 + col] = (_Float16)acc[ct][r];
            }
        }
    } else {
        // ---- partition: one 4096-edge tile per block, 8-edge int4 batches ----
        int sb = bid / 5;
        int base = sb * 4096;
        if (base >= E) return;
        int eend = base + 4096; if (eend > E) eend = E;
        for (int i = t; i < nbkt; i += 256) u.s.cnt[i] = 0;
        __syncthreads();
        // phase A: histogram (8 dst per thread per sweep, 2 int4 loads)
        for (int e0 = base + t * 8; e0 < eend; e0 += 2048) {
            if (e0 + 8 <= eend) {
                int4 d0 = *(const int4*)(dst + e0);
                int4 d1 = *(const int4*)(dst + e0 + 4);
                atomicAdd(&u.s.cnt[d0.x >> 9], 1); atomicAdd(&u.s.cnt[d0.y >> 9], 1);
                atomicAdd(&u.s.cnt[d0.z >> 9], 1); atomicAdd(&u.s.cnt[d0.w >> 9], 1);
                atomicAdd(&u.s.cnt[d1.x >> 9], 1); atomicAdd(&u.s.cnt[d1.y >> 9], 1);
                atomicAdd(&u.s.cnt[d1.z >> 9], 1); atomicAdd(&u.s.cnt[d1.w >> 9], 1);
            } else {
                for (int e = e0; e < eend; e++) atomicAdd(&u.s.cnt[dst[e] >> 9], 1);
            }
        }
        __syncthreads();
        // phase B: claim contiguous chunks
        for (int i = t; i < nbkt; i += 256) {
            u.s.off[i] = 0;
            int c = u.s.cnt[i];
            if (c > 0) u.s.gbase[i] = atomicAdd(&bktCnt[i], c);
        }
        __syncthreads();
        // phase C: packed scatter (8 edges per thread per sweep)
        for (int e0 = base + t * 8; e0 < eend; e0 += 2048) {
            if (e0 + 8 <= eend) {
                int4 s0 = *(const int4*)(src + e0);
                int4 s1 = *(const int4*)(src + e0 + 4);
                int4 d0 = *(const int4*)(dst + e0);
                int4 d1 = *(const int4*)(dst + e0 + 4);
                int ss[8] = {s0.x, s0.y, s0.z, s0.w, s1.x, s1.y, s1.z, s1.w};
                int dd[8] = {d0.x, d0.y, d0.z, d0.w, d1.x, d1.y, d1.z, d1.w};
#pragma unroll
                for (int j = 0; j < 8; j++) {
                    int b = dd[j] >> 9;
                    int slot = u.s.gbase[b] + atomicAdd(&u.s.off[b], 1);
                    unsigned p = ((unsigned)(dd[j] & 511) << 17) | (unsigned)ss[j];
                    if (slot < BKT_CAP) {
                        pairPart[(size_t)b * BKT_CAP + slot] = p;
                    } else {
                        int op = atomicAdd(ovfCnt, 1);
                        if (op < OVF_CAP) ovfBuf[op] = make_int2((int)p, b);
                    }
                }
            } else {
                for (int e = e0; e < eend; e++) {
                    int s = src[e], d = dst[e];
                    int b = d >> 9;
                    int slot = u.s.gbase[b] + atomicAdd(&u.s.off[b], 1);
                    unsigned p = ((unsigned)(d & 511) << 17) | (unsigned)s;
                    if (slot < BKT_CAP) {
                        pairPart[(size_t)b * BKT_CAP + slot] = p;
                    } else {
                        int op = atomicAdd(ovfCnt, 1);
                        if (op < OVF_CAP) ovfBuf[op] = make_int2((int)p, b);
                    }
                }
            }
        }
    }
}

// ---------------- bucket_process: base-scan + histogram + scan + deg/dinv/rowstart
//                  + srcSorted scatter + h1 scale — one kernel, one block per bucket ----------------
__global__ __launch_bounds__(512) void bucket_process_kernel(
        const unsigned* __restrict__ pairPart, const int* __restrict__ bktCnt,
        const int* __restrict__ ovfCnt, const int2* __restrict__ ovfBuf,
        int* __restrict__ deg, float* __restrict__ dinv, int* __restrict__ rowstart,
        int* __restrict__ srcSorted, _Float16* __restrict__ h1, int n, int nbkt) {
    __shared__ int hist[512];
    __shared__ float sdinv[512];
    int b = blockIdx.x;
    int t = threadIdx.x;

    // phase 0: bucket base = exclusive prefix of bktCnt (in-LDS 256-scan, redundant per block)
    if (t < 256) hist[t] = (t < nbkt) ? bktCnt[t] : 0;
    __syncthreads();
    for (int off = 1; off < 256; off <<= 1) {
        int add = (t < 256 && t >= off) ? hist[t - off] : 0;
        __syncthreads();
        if (t < 256) hist[t] += add;
        __syncthreads();
    }
    int myBase = hist[b] - bktCnt[b];   // exclusive
    __syncthreads();

    // phase 1: histogram bucket pairs into hist[512]
    hist[t] = 0;
    __syncthreads();
    int cnt = bktCnt[b];
    if (cnt > BKT_CAP) cnt = BKT_CAP;
    const unsigned* bp = pairPart + (size_t)b * BKT_CAP;
    for (int e0 = t * 4; e0 < cnt; e0 += 2048) {
        if (e0 + 4 <= cnt) {
            uint4 p = *(const uint4*)(bp + e0);
            atomicAdd(&hist[p.x >> 17], 1); atomicAdd(&hist[p.y >> 17], 1);
            atomicAdd(&hist[p.z >> 17], 1); atomicAdd(&hist[p.w >> 17], 1);
        } else {
            for (int e = e0; e < cnt; e++) atomicAdd(&hist[bp[e] >> 17], 1);
        }
    }
    int oc = *ovfCnt;
    if (oc > 0) {
        if (oc > OVF_CAP) oc = OVF_CAP;
        for (int i = t; i < oc; i += 512) {
            int2 p = ovfBuf[i];
            if (p.y == b) atomicAdd(&hist[((unsigned)p.x) >> 17], 1);
        }
    }
    __syncthreads();

    // phase 2: 512-wide inclusive scan -> deg/dinv/rowstart + cursors
    int v = hist[t];
#pragma unroll
    for (int off = 1; off < 512; off <<= 1) {
        int add = (t >= off) ? hist[t - off] : 0;
        __syncthreads();
        hist[t] += add;
        __syncthreads();
    }
    int cur = myBase + hist[t] - v;     // global rowstart for this node
    float dv = rsqrtf((float)(v + 1));  // +1 = self loop
    int node = (b << 9) + t;
    if (node < n) {
        deg[node] = v;
        dinv[node] = dv;
        rowstart[node] = cur;
    }
    sdinv[t] = dv;
    hist[t] = cur;                      // own slot only; becomes scatter cursor
    __syncthreads();

    // phase 3: scatter srcSorted (4-batched)
    for (int e0 = t * 4; e0 < cnt; e0 += 2048) {
        if (e0 + 4 <= cnt) {
            uint4 p = *(const uint4*)(bp + e0);
            int p0 = atomicAdd(&hist[p.x >> 17], 1);
            int p1 = atomicAdd(&hist[p.y >> 17], 1);
            int p2 = atomicAdd(&hist[p.z >> 17], 1);
            int p3 = atomicAdd(&hist[p.w >> 17], 1);
            srcSorted[p0] = (int)(p.x & SRC_MASK);
            srcSorted[p1] = (int)(p.y & SRC_MASK);
            srcSorted[p2] = (int)(p.z & SRC_MASK);
            srcSorted[p3] = (int)(p.w & SRC_MASK);
        } else {
            for (int e = e0; e < cnt; e++) {
                unsigned p = bp[e];
                int pos = atomicAdd(&hist[p >> 17], 1);
                srcSorted[pos] = (int)(p & SRC_MASK);
            }
        }
    }
    if (oc > 0) {
        for (int i = t; i < oc; i += 512) {
            int2 p = ovfBuf[i];
            if (p.y == b) {
                int pos = atomicAdd(&hist[((unsigned)p.x) >> 17], 1);
                srcSorted[pos] = (int)((unsigned)p.x & SRC_MASK);
            }
        }
    }

    // phase 4: scale this bucket's h1 rows by dinv (coalesced)
    int node0 = b << 9;
    int rows = n - node0; if (rows > 512) rows = 512;
    if (rows > 0) {
        int total = rows * 16;              // f16x8 slots
        f16x8* hrow = (f16x8*)(h1 + (size_t)node0 * 128);
        for (int i = t; i < total; i += 512) {
            float dvv = sdinv[i >> 4];
            f16x8 vv = hrow[i];
#pragma unroll
            for (int k = 0; k < 8; k++) vv[k] = (_Float16)((float)vv[k] * dvv);
            hrow[i] = vv;
        }
    }
}

// ---------------- gather1: h2 = relu(dg * agg(h1') + b1)  [16-deep load batches] ----------------
__global__ __launch_bounds__(256) void gather1_kernel(
        const int* __restrict__ srcS, const int* __restrict__ rowstart,
        const int* __restrict__ deg, const float* __restrict__ dinv,
        const _Float16* __restrict__ h1, const float* __restrict__ b1,
        float* __restrict__ h2, int n) {
    int t = threadIdx.x;
    int g = __builtin_amdgcn_readfirstlane(blockIdx.x * 4 + (t >> 6));
    int lane = t & 63;
    if (g >= n) return;

    float dg = dinv[g];
    half2v sv0 = ((const half2v*)(h1 + (size_t)g * 128))[lane];  // self term (pre-scaled)
    float2 acc = make_float2((float)sv0.x, (float)sv0.y);
    int beg = rowstart[g], end = beg + deg[g];
    int e = beg;
    while (e < end) {
        int rem = end - e;
        int sv = (lane < rem) ? srcS[e + lane] : 0;   // 1 coalesced load / 64 edges
        int chunk = rem < 64 ? rem : 64;
        int j = 0;
        for (; j + 16 <= chunk; j += 16) {            // 16 loads in flight
            int s0 = __shfl(sv, j + 0),  s1 = __shfl(sv, j + 1);
            int s2 = __shfl(sv, j + 2),  s3 = __shfl(sv, j + 3);
            int s4 = __shfl(sv, j + 4),  s5 = __shfl(sv, j + 5);
            int s6 = __shfl(sv, j + 6),  s7 = __shfl(sv, j + 7);
            int s8 = __shfl(sv, j + 8),  s9 = __shfl(sv, j + 9);
            int sA = __shfl(sv, j + 10), sB = __shfl(sv, j + 11);
            int sC = __shfl(sv, j + 12), sD = __shfl(sv, j + 13);
            int sE = __shfl(sv, j + 14), sF = __shfl(sv, j + 15);
            half2v u0 = ((const half2v*)(h1 + (size_t)s0 * 128))[lane];
            half2v u1 = ((const half2v*)(h1 + (size_t)s1 * 128))[lane];
            half2v u2 = ((const half2v*)(h1 + (size_t)s2 * 128))[lane];
            half2v u3 = ((const half2v*)(h1 + (size_t)s3 * 128))[lane];
            half2v u4 = ((const half2v*)(h1 + (size_t)s4 * 128))[lane];
            half2v u5 = ((const half2v*)(h1 + (size_t)s5 * 128))[lane];
            half2v u6 = ((const half2v*)(h1 + (size_t)s6 * 128))[lane];
            half2v u7 = ((const half2v*)(h1 + (size_t)s7 * 128))[lane];
            half2v u8 = ((const half2v*)(h1 + (size_t)s8 * 128))[lane];
            half2v u9 = ((const half2v*)(h1 + (size_t)s9 * 128))[lane];
            half2v uA = ((const half2v*)(h1 + (size_t)sA * 128))[lane];
            half2v uB = ((const half2v*)(h1 + (size_t)sB * 128))[lane];
            half2v uC = ((const half2v*)(h1 + (size_t)sC * 128))[lane];
            half2v uD = ((const half2v*)(h1 + (size_t)sD * 128))[lane];
            half2v uE = ((const half2v*)(h1 + (size_t)sE * 128))[lane];
            half2v uF = ((const half2v*)(h1 + (size_t)sF * 128))[lane];
            acc.x += (float)u0.x; acc.y += (float)u0.y;
            acc.x += (float)u1.x; acc.y += (float)u1.y;
            acc.x += (float)u2.x; acc.y += (float)u2.y;
            acc.x += (float)u3.x; acc.y += (float)u3.y;
            acc.x += (float)u4.x; acc.y += (float)u4.y;
            acc.x += (float)u5.x; acc.y += (float)u5.y;
            acc.x += (float)u6.x; acc.y += (float)u6.y;
            acc.x += (float)u7.x; acc.y += (float)u7.y;
            acc.x += (float)u8.x; acc.y += (float)u8.y;
            acc.x += (float)u9.x; acc.y += (float)u9.y;
            acc.x += (float)uA.x; acc.y += (float)uA.y;
            acc.x += (float)uB.x; acc.y += (float)uB.y;
            acc.x += (float)uC.x; acc.y += (float)uC.y;
            acc.x += (float)uD.x; acc.y += (float)uD.y;
            acc.x += (float)uE.x; acc.y += (float)uE.y;
            acc.x += (float)uF.x; acc.y += (float)uF.y;
        }
        for (; j + 8 <= chunk; j += 8) {
            int s0 = __shfl(sv, j + 0), s1 = __shfl(sv, j + 1);
            int s2 = __shfl(sv, j + 2), s3 = __shfl(sv, j + 3);
            int s4 = __shfl(sv, j + 4), s5 = __shfl(sv, j + 5);
            int s6 = __shfl(sv, j + 6), s7 = __shfl(sv, j + 7);
            half2v u0 = ((const half2v*)(h1 + (size_t)s0 * 128))[lane];
            half2v u1 = ((const half2v*)(h1 + (size_t)s1 * 128))[lane];
            half2v u2 = ((const half2v*)(h1 + (size_t)s2 * 128))[lane];
            half2v u3 = ((const half2v*)(h1 + (size_t)s3 * 128))[lane];
            half2v u4 = ((const half2v*)(h1 + (size_t)s4 * 128))[lane];
            half2v u5 = ((const half2v*)(h1 + (size_t)s5 * 128))[lane];
            half2v u6 = ((const half2v*)(h1 + (size_t)s6 * 128))[lane];
            half2v u7 = ((const half2v*)(h1 + (size_t)s7 * 128))[lane];
            acc.x += (float)u0.x; acc.y += (float)u0.y;
            acc.x += (float)u1.x; acc.y += (float)u1.y;
            acc.x += (float)u2.x; acc.y += (float)u2.y;
            acc.x += (float)u3.x; acc.y += (float)u3.y;
            acc.x += (float)u4.x; acc.y += (float)u4.y;
            acc.x += (float)u5.x; acc.y += (float)u5.y;
            acc.x += (float)u6.x; acc.y += (float)u6.y;
            acc.x += (float)u7.x; acc.y += (float)u7.y;
        }
        for (; j < chunk; j++) {
            int s = __shfl(sv, j);
            half2v u = ((const half2v*)(h1 + (size_t)s * 128))[lane];
            acc.x += (float)u.x; acc.y += (float)u.y;
        }
        e += chunk;
    }
    float2 b = ((const float2*)b1)[lane];
    acc.x = fmaxf(dg * acc.x + b.x, 0.f);
    acc.y = fmaxf(dg * acc.y + b.y, 0.f);
    ((float2*)(h2 + (size_t)g * 128))[lane] = acc;
}

// ---------------- GEMM2: h3'[N,64] = fp16( dinv * (h2[N,128] @ W2[128,64]) ) ----------------
__global__ __launch_bounds__(256) void gemm_nk64(const float* __restrict__ x,
                                                 const float* __restrict__ W,
                                                 const float* __restrict__ dinv,
                                                 _Float16* __restrict__ h, int n) {
    __shared__ float xs[32][128];
    int t = threadIdx.x;
    int node0 = blockIdx.x * 32;
#pragma unroll
    for (int i = 0; i < 4; i++) {
        int fi = t + 256 * i;
        int row = fi >> 5, cv = fi & 31;
        float4 v = make_float4(0.f, 0.f, 0.f, 0.f);
        if (node0 + row < n) v = ((const float4*)x)[(size_t)(node0 + row) * 32 + cv];
        ((float4*)(&xs[0][0]))[fi] = v;
    }
    __syncthreads();

    int tx = t & 15, ty = t >> 4;
    int c0 = tx * 4;
    float acc[2][4];
#pragma unroll
    for (int i = 0; i < 2; i++)
#pragma unroll
        for (int j = 0; j < 4; j++) acc[i][j] = 0.f;

    for (int k = 0; k < 128; k++) {
        float4 w = *(const float4*)(W + k * 64 + c0);
#pragma unroll
        for (int i = 0; i < 2; i++) {
            float xval = xs[ty + 16 * i][k];
            acc[i][0] += xval * w.x;
            acc[i][1] += xval * w.y;
            acc[i][2] += xval * w.z;
            acc[i][3] += xval * w.w;
        }
    }
#pragma unroll
    for (int i = 0; i < 2; i++) {
        int node = node0 + ty + 16 * i;
        if (node < n) {
            float dv = dinv[node];
            half4v hv;
            hv.x = (_Float16)(acc[i][0] * dv);
            hv.y = (_Float16)(acc[i][1] * dv);
            hv.z = (_Float16)(acc[i][2] * dv);
            hv.w = (_Float16)(acc[i][3] * dv);
            *(half4v*)(h + (size_t)node * 64 + c0) = hv;
        }
    }
}

// ---------------- gather2: out = dg * agg(h3') + b2  [16-deep load batches] ----------------
__global__ __launch_bounds__(256) void gather2_kernel(
        const int* __restrict__ srcS, const int* __restrict__ rowstart,
        const int* __restrict__ deg, const float* __restrict__ dinv,
        const _Float16* __restrict__ h3, const float* __restrict__ b2,
        float* __restrict__ out, int n) {
    int t = threadIdx.x;
    int g = __builtin_amdgcn_readfirstlane(blockIdx.x * 4 + (t >> 6));
    int lane = t & 63;
    if (g >= n) return;
    float dg = dinv[g];
    float acc = (float)h3[(size_t)g * 64 + lane];   // self term (pre-scaled)
    int beg = rowstart[g], end = beg + deg[g];
    int e = beg;
    while (e < end) {
        int rem = end - e;
        int sv = (lane < rem) ? srcS[e + lane] : 0;
        int chunk = rem < 64 ? rem : 64;
        int j = 0;
        for (; j + 16 <= chunk; j += 16) {
            int s0 = __shfl(sv, j + 0),  s1 = __shfl(sv, j + 1);
            int s2 = __shfl(sv, j + 2),  s3 = __shfl(sv, j + 3);
            int s4 = __shfl(sv, j + 4),  s5 = __shfl(sv, j + 5);
            int s6 = __shfl(sv, j + 6),  s7 = __shfl(sv, j + 7);
            int s8 = __shfl(sv, j + 8),  s9 = __shfl(sv, j + 9);
            int sA = __shfl(sv, j + 10), sB = __shfl(sv, j + 11);
            int sC = __shfl(sv, j + 12), sD = __shfl(sv, j + 13);
            int sE = __shfl(sv, j + 14), sF = __shfl(sv, j + 15);
            float u0 = (float)h3[(size_t)s0 * 64 + lane];
            float u1 = (float)h3[(size_t)s1 * 64 + lane];
            float u2 = (float)h3[(size_t)s2 * 64 + lane];
            float u3 = (float)h3[(size_t)s3 * 64 + lane];
            float u4 = (float)h3[(size_t)s4 * 64 + lane];
            float u5 = (float)h3[(size_t)s5 * 64 + lane];
            float u6 = (float)h3[(size_t)s6 * 64 + lane];
            float u7 = (float)h3[(size_t)s7 * 64 + lane];
            float u8 = (float)h3[(size_t)s8 * 64 + lane];
            float u9 = (float)h3[(size_t)s9 * 64 + lane];
            float uA = (float)h3[(size_t)sA * 64 + lane];
            float uB = (float)h3[(size_t)sB * 64 + lane];
            float uC = (float)h3[(size_t)sC * 64 + lane];
            float uD = (float)h3[(size_t)sD * 64 + lane];
            float uE = (float)h3[(size_t)sE * 64 + lane];
            float uF = (float)h3[(size_t)sF * 64 + lane];
            acc += u0 + u1 + u2 + u3 + u4 + u5 + u6 + u7
                 + u8 + u9 + uA + uB + uC + uD + uE + uF;
        }
        for (; j + 8 <= chunk; j += 8) {
            int s0 = __shfl(sv, j + 0), s1 = __shfl(sv, j + 1);
            int s2 = __shfl(sv, j + 2), s3 = __shfl(sv, j + 3);
            int s4 = __shfl(sv, j + 4), s5 = __shfl(sv, j + 5);
            int s6 = __shfl(sv, j + 6), s7 = __shfl(sv, j + 7);
            float u0 = (float)h3[(size_t)s0 * 64 + lane];
            float u1 = (float)h3[(size_t)s1 * 64 + lane];
            float u2 = (float)h3[(size_t)s2 * 64 + lane];
            float u3 = (float)h3[(size_t)s3 * 64 + lane];
            float u4 = (float)h3[(size_t)s4 * 64 + lane];
            float u5 = (float)h3[(size_t)s5 * 64 + lane];
            float u6 = (float)h3[(size_t)s6 * 64 + lane];
            float u7 = (float)h3[(size_t)s7 * 64 + lane];
            acc += u0 + u1 + u2 + u3 + u4 + u5 + u6 + u7;
        }
        for (; j < chunk; j++) {
            int s = __shfl(sv, j);
            acc += (float)h3[(size_t)s * 64 + lane];
        }
        e += chunk;
    }
    out[(size_t)g * 64 + lane] = dg * acc + b2[lane];
}

extern "C" void kernel_launch(void* const* d_in, const int* in_sizes, int n_in,
                              void* d_out, int out_size, void* d_ws, size_t ws_size,
                              hipStream_t stream) {
    const float* x  = (const float*)d_in[0];
    const int*   ei = (const int*)d_in[1];
    const float* W1 = (const float*)d_in[2];
    const float* b1 = (const float*)d_in[3];
    const float* W2 = (const float*)d_in[4];
    const float* b2 = (const float*)d_in[5];
    float* out = (float*)d_out;

    const int n = in_sizes[0] / 128;   // 100000
    const int E = in_sizes[1] / 2;     // 1600000
    const int* src = ei;
    const int* dst = ei + E;
    const int nbkt = (n + 511) >> 9;   // 196 coarse buckets (512 nodes each)

    char* ws = (char*)d_ws;
    size_t off = 0;
    auto carve = [&](size_t bytes) -> char* {
        char* p = ws + off;
        off += (bytes + 255) & ~(size_t)255;
        return p;
    };
    // bktCnt/ovfCnt contiguous -> single small memset
    int*   bktCnt    = (int*)carve((size_t)NBKT_MAX * 4);
    int*   ovfCnt    = (int*)carve(4);
    size_t msz       = (size_t)((char*)ovfCnt - (char*)bktCnt) + 256;
    int*   deg       = (int*)carve((size_t)n * 4);       // written by bucket_process
    float* dinv      = (float*)carve((size_t)n * 4);
    int*   rowstart  = (int*)carve((size_t)n * 4);
    int*   srcSorted = (int*)carve((size_t)E * 4);
    _Float16* Wt     = (_Float16*)carve((size_t)128 * 128 * 2);    // W1^T fp16
    int2*  ovfBuf    = (int2*)carve((size_t)OVF_CAP * 8);
    _Float16* h1     = (_Float16*)carve((size_t)n * 128 * 2);      // x@W1 fp16 (scaled in-place); then h3
    float* bufB      = (float*)carve((size_t)n * 128 * 4);         // pairPart (pass1-2), then h2
    unsigned* pairPart = (unsigned*)bufB;  // 12.8MB <= 51.2MB, dead before gather1 writes h2
    _Float16* h3     = h1;                 // gemm_nk64 writes after gather1 finishes reading h1

    hipMemsetAsync(bktCnt, 0, msz, stream);

    wcast_kernel<<<64, 256, 0, stream>>>(W1, Wt);

    // fused partition | gemm1 (4 GEMM : 1 sort per 5-group)
    int sortBlocks = (E + 4095) / 4096;             // 391
    int gemmBlocks = (n + 63) / 64;                 // 1563
    int gGroups = (gemmBlocks + 3) / 4;             // 391
    int groups = (sortBlocks > gGroups) ? sortBlocks : gGroups;
    int G = groups * 5;
    part_gemm1_kernel<<<G, 256, 0, stream>>>(src, dst, bktCnt, ovfCnt, ovfBuf,
                                             pairPart, E, x, Wt, h1, n, nbkt);

    // one kernel: base-scan + histogram + scan + deg/dinv/rowstart + scatter + h1 scale
    bucket_process_kernel<<<nbkt, 512, 0, stream>>>(pairPart, bktCnt, ovfCnt, ovfBuf,
                                                    deg, dinv, rowstart, srcSorted,
                                                    h1, n, nbkt);

    // layer 1 aggregation: h2 = relu(dg * agg(h1') + b1)
    gather1_kernel<<<(n + 3) / 4, 256, 0, stream>>>(srcSorted, rowstart, deg, dinv,
                                                    h1, b1, bufB, n);

    // layer 2: h3' = fp16(dinv * (h2@W2)) (reuses h1 buffer) ; out = dg * agg(h3') + b2
    gemm_nk64<<<(n + 31) / 32, 256, 0, stream>>>(bufB, W2, dinv, h3, n);
    gather2_kernel<<<(n + 3) / 4, 256, 0, stream>>>(srcSorted, rowstart, deg, dinv,
                                                    h3, b2, out, n);
}